// Round 7
// baseline (1031.316 us; speedup 1.0000x reference)
//
#include <hip/hip_runtime.h>
#include <hip/hip_bf16.h>

#define N_NODES 100000
#define N_EDGES 1600000
#define HDIM    128
#define NLAYER  6
#define NGRAPH  128
#define NCLASS  10
#define BN_EPS  1e-5f

#define SCAN_CHUNK 1024
#define SCAN_NB    ((N_NODES + SCAN_CHUNK - 1) / SCAN_CHUNK)   // 98
#define POOL_SPLIT 16
#define BUCKET_W 12500                                          // nodes per XCD bucket

#define GBM 128
#define NBLK_G ((N_NODES + GBM - 1) / GBM)                     // 782

typedef __attribute__((ext_vector_type(8))) short short8v;
typedef __attribute__((ext_vector_type(4))) float f32x4;
typedef __attribute__((ext_vector_type(4))) int int4v;

__device__ __forceinline__ float b2f(unsigned short h) {
    return __uint_as_float(((unsigned int)h) << 16);
}
__device__ __forceinline__ unsigned short f2b(float f) {
    unsigned int u = __float_as_uint(f);
    u += 0x7FFF + ((u >> 16) & 1);          // RNE
    return (unsigned short)(u >> 16);
}
__device__ __forceinline__ void gl_lds16(const void* g, void* l) {
    __builtin_amdgcn_global_load_lds((const __attribute__((address_space(1))) unsigned int*)g,
                                     (__attribute__((address_space(3))) unsigned int*)l,
                                     16, 0, 0);
}
__device__ __forceinline__ short8v bn_pack(short8v v, float4 scA, float4 scB,
                                           float4 shA, float4 shB) {
    short8v o;
    o[0] = (short)f2b(fmaxf(0.f, b2f((unsigned short)v[0]) * scA.x + shA.x));
    o[1] = (short)f2b(fmaxf(0.f, b2f((unsigned short)v[1]) * scA.y + shA.y));
    o[2] = (short)f2b(fmaxf(0.f, b2f((unsigned short)v[2]) * scA.z + shA.z));
    o[3] = (short)f2b(fmaxf(0.f, b2f((unsigned short)v[3]) * scA.w + shA.w));
    o[4] = (short)f2b(fmaxf(0.f, b2f((unsigned short)v[4]) * scB.x + shB.x));
    o[5] = (short)f2b(fmaxf(0.f, b2f((unsigned short)v[5]) * scB.y + shB.y));
    o[6] = (short)f2b(fmaxf(0.f, b2f((unsigned short)v[6]) * scB.z + shB.z));
    o[7] = (short)f2b(fmaxf(0.f, b2f((unsigned short)v[7]) * scB.w + shB.w));
    return o;
}

// ---------------- CSR build (XCD-bucketed writes, nt int4 streams) ----------------

__global__ void __launch_bounds__(256) k_deg_b(const int* __restrict__ dst,
                                               int* __restrict__ deg) {
    const int res = blockIdx.x & 7;
    const int lo  = res * BUCKET_W;
    const int bi  = blockIdx.x >> 3;
    const int stride = (gridDim.x >> 3) * 256;
    const int4v* d4p = (const int4v*)dst;
    for (int i = bi * 256 + threadIdx.x; i < N_EDGES / 4; i += stride) {
        int4v d = __builtin_nontemporal_load(d4p + i);
        if ((unsigned)(d[0] - lo) < BUCKET_W) atomicAdd(&deg[d[0]], 1);
        if ((unsigned)(d[1] - lo) < BUCKET_W) atomicAdd(&deg[d[1]], 1);
        if ((unsigned)(d[2] - lo) < BUCKET_W) atomicAdd(&deg[d[2]], 1);
        if ((unsigned)(d[3] - lo) < BUCKET_W) atomicAdd(&deg[d[3]], 1);
    }
}

__global__ void __launch_bounds__(256) k_fill_b(const int* __restrict__ src,
                                                const int* __restrict__ dst,
                                                const int* __restrict__ row_off,
                                                int* __restrict__ cursor,
                                                int* __restrict__ col) {
    const int res = blockIdx.x & 7;
    const int lo  = res * BUCKET_W;
    const int bi  = blockIdx.x >> 3;
    const int stride = (gridDim.x >> 3) * 256;
    const int4v* d4p = (const int4v*)dst;
    const int4v* s4p = (const int4v*)src;
    for (int i = bi * 256 + threadIdx.x; i < N_EDGES / 4; i += stride) {
        int4v d = __builtin_nontemporal_load(d4p + i);
        bool m0 = (unsigned)(d[0] - lo) < BUCKET_W;
        bool m1 = (unsigned)(d[1] - lo) < BUCKET_W;
        bool m2 = (unsigned)(d[2] - lo) < BUCKET_W;
        bool m3 = (unsigned)(d[3] - lo) < BUCKET_W;
        if (m0 | m1 | m2 | m3) {
            int4v s = __builtin_nontemporal_load(s4p + i);
            if (m0) { int pos = row_off[d[0]] + atomicAdd(&cursor[d[0]], 1); col[pos] = s[0]; }
            if (m1) { int pos = row_off[d[1]] + atomicAdd(&cursor[d[1]], 1); col[pos] = s[1]; }
            if (m2) { int pos = row_off[d[2]] + atomicAdd(&cursor[d[2]], 1); col[pos] = s[2]; }
            if (m3) { int pos = row_off[d[3]] + atomicAdd(&cursor[d[3]], 1); col[pos] = s[3]; }
        }
    }
}

__global__ void k_blocksum(const int* __restrict__ deg, int* __restrict__ partial) {
    int b = blockIdx.x, t = threadIdx.x;
    int s = 0;
    for (int i = 0; i < 4; ++i) {
        int g = b * SCAN_CHUNK + t * 4 + i;
        if (g < N_NODES) s += deg[g];
    }
    __shared__ int red[256];
    red[t] = s; __syncthreads();
    for (int off = 128; off > 0; off >>= 1) {
        if (t < off) red[t] += red[t + off];
        __syncthreads();
    }
    if (t == 0) partial[b] = red[0];
}

__global__ void k_scanpart(int* __restrict__ partial) {
    if (threadIdx.x == 0 && blockIdx.x == 0) {
        int acc = 0;
        for (int i = 0; i < SCAN_NB; ++i) { int v = partial[i]; partial[i] = acc; acc += v; }
    }
}

__global__ void k_scan2(const int* __restrict__ deg, const int* __restrict__ partial,
                        int* __restrict__ row_off) {
    int b = blockIdx.x, t = threadIdx.x;
    int base = b * SCAN_CHUNK;
    int v[4]; int s = 0;
    for (int i = 0; i < 4; ++i) {
        int g = base + t * 4 + i;
        v[i] = (g < N_NODES) ? deg[g] : 0;
        s += v[i];
    }
    __shared__ int ts[256];
    ts[t] = s; __syncthreads();
    for (int off = 1; off < 256; off <<= 1) {
        int x = (t >= off) ? ts[t - off] : 0;
        __syncthreads();
        ts[t] += x;
        __syncthreads();
    }
    int excl = (t > 0 ? ts[t - 1] : 0) + partial[b];
    for (int i = 0; i < 4; ++i) {
        int g = base + t * 4 + i;
        if (g < N_NODES) row_off[g] = excl;
        excl += v[i];
    }
    if (b == 0 && t == 0) row_off[N_NODES] = N_EDGES;
}

// ---------------- one-time converts ----------------

__global__ void __launch_bounds__(256) k_cvt_x(const float* __restrict__ x,
                                               unsigned short* __restrict__ Xb) {
    int idx = blockIdx.x * 256 + threadIdx.x;          // < N*H/4
    f32x4 v = __builtin_nontemporal_load(((const f32x4*)x) + idx);
    ushort4 o = { f2b(v[0]), f2b(v[1]), f2b(v[2]), f2b(v[3]) };
    ((ushort4*)Xb)[idx] = o;
}

// Wtb[l][n][kk] (kk<128 -> Wl[l][kk][n], else Wr[l][kk-128][n]), bf16
__global__ void __launch_bounds__(256) k_cvt_w(const float* __restrict__ Wl,
                                               const float* __restrict__ Wr,
                                               unsigned short* __restrict__ Wtb) {
    int idx = blockIdx.x * 256 + threadIdx.x;          // < 6*128*256
    int kk = idx & 255;
    int n  = (idx >> 8) & 127;
    int l  = idx >> 15;
    float v = (kk < HDIM) ? Wl[l * HDIM * HDIM + kk * HDIM + n]
                          : Wr[l * HDIM * HDIM + (kk - HDIM) * HDIM + n];
    Wtb[idx] = f2b(v);
}

// ---------------- fused agg + GEMM + BN-stat (one kernel per layer) ----------------
// 512 threads (8 waves), 128 rows/block.
// LDS: [0,32KB) agg A-tile (4 steps x [128 rows][64B], slot-swizzled)
//      [32KB,48KB) own-half dbuf 2x8KB
//      [48KB,64KB) W dbuf 2x8KB
template<bool BN>
__global__ void __launch_bounds__(512, 4) k_fused(const unsigned short* __restrict__ Hsrc,
                                                  const float* __restrict__ scsh,
                                                  const int* __restrict__ row_off,
                                                  const int* __restrict__ col,
                                                  const unsigned short* __restrict__ Wtb,
                                                  const float* __restrict__ bl,
                                                  unsigned short* __restrict__ Hb,
                                                  float* __restrict__ pstat) {
    __shared__ __align__(16) char smem[65536];
    char* aggT = smem;
    char* ownB = smem + 32768;
    char* wB   = smem + 49152;

    const int tid  = threadIdx.x;
    const int bm   = blockIdx.x * GBM;
    const int wv   = tid >> 6;          // 0..7
    const int lane = tid & 63;
    const int li   = lane & 15, hi = lane >> 4;

    // stage W step 0 early (completes under the gather; syncthreads drains it)
    {
        int n = tid >> 2, sk = tid & 3;
        gl_lds16((const char*)(Wtb + (size_t)n * 256) + (((sk ^ (n & 3)) & 3) << 4),
                 wB + wv * 1024);
    }

    // ---- phase 1: gather-aggregate 128 rows into aggT (bf16, step-swizzled) ----
    {
        const int t  = tid & 15;
        const int c8 = t * 8;
        float sc[8], sh[8];
        if (BN) {
#pragma unroll
            for (int k = 0; k < 8; ++k) { sc[k] = scsh[c8 + k]; sh[k] = scsh[HDIM + c8 + k]; }
        }
#pragma unroll
        for (int pass = 0; pass < 4; ++pass) {
            int r = pass * 32 + (tid >> 4);
            int node = bm + r;
            float a[8] = {};
            float w = 0.f;
            if (node < N_NODES) {
                int s = row_off[node], e = row_off[node + 1];
                int p = s;
                for (; p + 8 <= e; p += 8) {
                    int nb[8];
#pragma unroll
                    for (int j = 0; j < 8; ++j) nb[j] = col[p + j];
                    short8v v[8];
#pragma unroll
                    for (int j = 0; j < 8; ++j)
                        v[j] = *(const short8v*)(Hsrc + (size_t)nb[j] * HDIM + c8);
#pragma unroll
                    for (int j = 0; j < 8; ++j)
#pragma unroll
                        for (int k = 0; k < 8; ++k) {
                            float f = b2f((unsigned short)v[j][k]);
                            a[k] += BN ? fmaxf(0.f, f * sc[k] + sh[k]) : f;
                        }
                }
                if (p + 4 <= e) {
                    int nb[4];
#pragma unroll
                    for (int j = 0; j < 4; ++j) nb[j] = col[p + j];
                    short8v v[4];
#pragma unroll
                    for (int j = 0; j < 4; ++j)
                        v[j] = *(const short8v*)(Hsrc + (size_t)nb[j] * HDIM + c8);
#pragma unroll
                    for (int j = 0; j < 4; ++j)
#pragma unroll
                        for (int k = 0; k < 8; ++k) {
                            float f = b2f((unsigned short)v[j][k]);
                            a[k] += BN ? fmaxf(0.f, f * sc[k] + sh[k]) : f;
                        }
                    p += 4;
                }
                for (; p < e; ++p) {
                    short8v v0 = *(const short8v*)(Hsrc + (size_t)col[p] * HDIM + c8);
#pragma unroll
                    for (int k = 0; k < 8; ++k) {
                        float f = b2f((unsigned short)v0[k]);
                        a[k] += BN ? fmaxf(0.f, f * sc[k] + sh[k]) : f;
                    }
                }
                w = (e > s) ? 1.0f / (float)(e - s) : 0.f;
            }
            short8v o;
#pragma unroll
            for (int k = 0; k < 8; ++k) o[k] = (short)f2b(a[k] * w);
            // step = t>>2, slot = t&3, row r
            *(short8v*)(aggT + (t >> 2) * 8192 + r * 64 + ((((t & 3) ^ (r & 3)) & 3) << 4)) = o;
        }
    }
    __syncthreads();

    // ---- phase 2: K-loop, steps 0..3 agg (LDS-resident), 4..7 own (reg-staged dbuf) ----
    f32x4 acc[8] = {};
    const int rr = tid >> 2, skv = tid & 3;
    const int swz2 = ((skv ^ (rr & 3)) << 4);

    int wbuf = 0;
    for (int step = 0; step < 8; ++step) {
        if (step < 7) {
            int k0 = (step + 1) * 32;
            int n = tid >> 2, sk = tid & 3;
            gl_lds16((const char*)(Wtb + (size_t)n * 256 + k0) + (((sk ^ (n & 3)) & 3) << 4),
                     wB + (wbuf ^ 1) * 8192 + wv * 1024);
        }
        short8v rv; int c0 = 0; bool rs = false;
        if (step >= 3 && step < 7) {
            rs = true;
            c0 = (step - 3) * 32 + skv * 8;
            int row = bm + rr; if (row >= N_NODES) row = N_NODES - 1;
            rv = *(const short8v*)(Hsrc + (size_t)row * HDIM + c0);
        }

        char* bA = (step < 4) ? (aggT + step * 8192) : (ownB + ((step - 4) & 1) * 8192);
        char* bW = wB + wbuf * 8192;
        short8v afr, bfr[8];
        {
            int r = wv * 16 + li;
            afr = *(const short8v*)(bA + r * 64 + ((hi ^ (r & 3)) << 4));
        }
#pragma unroll
        for (int nf = 0; nf < 8; ++nf) {
            int n = nf * 16 + li;
            bfr[nf] = *(const short8v*)(bW + n * 64 + ((hi ^ (n & 3)) << 4));
        }
#pragma unroll
        for (int nf = 0; nf < 8; ++nf)
            acc[nf] = __builtin_amdgcn_mfma_f32_16x16x32_bf16(afr, bfr[nf], acc[nf], 0, 0, 0);

        if (rs) {
            short8v ov;
            if (BN) {
                float4 scA = *(const float4*)&scsh[c0];
                float4 scB = *(const float4*)&scsh[c0 + 4];
                float4 shA = *(const float4*)&scsh[HDIM + c0];
                float4 shB = *(const float4*)&scsh[HDIM + c0 + 4];
                ov = bn_pack(rv, scA, scB, shA, shB);
            } else {
                ov = rv;
            }
            *(short8v*)(ownB + ((step - 3) & 1) * 8192 + rr * 64 + swz2) = ov;
        }
        __syncthreads();
        wbuf ^= 1;
    }

    // ---- epilogue: bias, store bf16 H, BN-stat partials ----
    float* st = (float*)smem;    // overlay on aggT: [0,1024) sums, [1024,2048) sqs
#pragma unroll
    for (int nf = 0; nf < 8; ++nf) {
        int c = nf * 16 + li;
        float bb = bl[c];
        float ls = 0.f, lq = 0.f;
        int row0 = bm + wv * 16 + hi * 4;
#pragma unroll
        for (int j = 0; j < 4; ++j) {
            int row = row0 + j;
            if (row < N_NODES) {
                float v = acc[nf][j] + bb;
                Hb[(size_t)row * HDIM + c] = f2b(v);
                ls += v; lq += v * v;
            }
        }
        ls += __shfl_xor(ls, 16); ls += __shfl_xor(ls, 32);
        lq += __shfl_xor(lq, 16); lq += __shfl_xor(lq, 32);
        if (hi == 0) {
            st[wv * 128 + c] = ls;
            st[1024 + wv * 128 + c] = lq;
        }
    }
    __syncthreads();
    if (tid < 128) {
        float s = 0.f;
#pragma unroll
        for (int w8 = 0; w8 < 8; ++w8) s += st[w8 * 128 + tid];
        pstat[blockIdx.x * 256 + tid] = s;
    } else if (tid < 256) {
        int c = tid - 128;
        float q = 0.f;
#pragma unroll
        for (int w8 = 0; w8 < 8; ++w8) q += st[1024 + w8 * 128 + c];
        pstat[blockIdx.x * 256 + tid] = q;
    }
}

__global__ void __launch_bounds__(256) k_red1(const float* __restrict__ pstat,
                                              float* __restrict__ red32) {
    int c = threadIdx.x, b = blockIdx.x;
    float s = 0.f;
    for (int r = b; r < NBLK_G; r += 32) s += pstat[r * 256 + c];
    red32[b * 256 + c] = s;
}

__global__ void __launch_bounds__(128) k_stats_final(const float* __restrict__ red32,
                                                     const float* __restrict__ gamma,
                                                     const float* __restrict__ beta,
                                                     float* __restrict__ scsh) {
    int c = threadIdx.x;
    float s = 0.f, q = 0.f;
    for (int r = 0; r < 32; ++r) { s += red32[r * 256 + c]; q += red32[r * 256 + 128 + c]; }
    float mu = s / (float)N_NODES;
    float var = q / (float)N_NODES - mu * mu;
    float rs = rsqrtf(var + BN_EPS);
    float sc = gamma[c] * rs;
    scsh[c] = sc;
    scsh[HDIM + c] = beta[c] - mu * sc;
}

// ---------------- pooling + classifier ----------------

__global__ void k_gbound(const int* __restrict__ batch, int* __restrict__ gb) {
    int t = blockIdx.x * 64 + threadIdx.x;
    if (t > NGRAPH) return;
    int lo = 0, hi = N_NODES;
    while (lo < hi) { int mid = (lo + hi) >> 1; if (batch[mid] < t) lo = mid + 1; else hi = mid; }
    gb[t] = lo;
}

// pool over bn_relu(H_final) applied on the fly
__global__ void __launch_bounds__(128) k_pool_part(const unsigned short* __restrict__ Hb,
                                                   const float* __restrict__ scsh,
                                                   const int* __restrict__ gb,
                                                   float* __restrict__ ppart) {
    int g = blockIdx.x, sp = blockIdx.y;
    int c = threadIdx.x;
    float sc = scsh[c], sh = scsh[HDIM + c];
    int s = gb[g], e = gb[g + 1];
    float acc = 0.f;
    for (int i = s + sp; i < e; i += POOL_SPLIT)
        acc += fmaxf(0.f, b2f(Hb[(size_t)i * HDIM + c]) * sc + sh);
    ppart[(g * POOL_SPLIT + sp) * HDIM + c] = acc;
}

__global__ void __launch_bounds__(128) k_pool_final(const int* __restrict__ gb,
                                                    const float* __restrict__ ppart,
                                                    float* __restrict__ pooled) {
    int g = blockIdx.x, c = threadIdx.x;
    float s = 0.f;
    for (int sp = 0; sp < POOL_SPLIT; ++sp) s += ppart[(g * POOL_SPLIT + sp) * HDIM + c];
    int cnt = gb[g + 1] - gb[g]; if (cnt < 1) cnt = 1;
    pooled[g * HDIM + c] = s / (float)cnt;
}

__global__ void __launch_bounds__(128) k_lin(const float* __restrict__ pooled,
                                             const float* __restrict__ W,
                                             const float* __restrict__ bvec,
                                             float* __restrict__ out) {
    __shared__ float p[HDIM];
    int g = blockIdx.x, t = threadIdx.x;
    p[t] = pooled[g * HDIM + t];
    __syncthreads();
    if (t < NCLASS) {
        float acc = bvec[t];
        for (int k = 0; k < HDIM; ++k) acc += p[k] * W[k * NCLASS + t];
        out[g * NCLASS + t] = acc;
    }
}

// ---------------- launch ----------------

extern "C" void kernel_launch(void* const* d_in, const int* in_sizes, int n_in,
                              void* d_out, int out_size, void* d_ws, size_t ws_size,
                              hipStream_t stream) {
    const float* x     = (const float*)d_in[0];
    const int*   eidx  = (const int*)d_in[1];
    const int*   batch = (const int*)d_in[2];
    const float* Wl    = (const float*)d_in[3];
    const float* bl    = (const float*)d_in[4];
    const float* Wr    = (const float*)d_in[5];
    const float* gamma = (const float*)d_in[6];
    const float* beta  = (const float*)d_in[7];
    const float* linW  = (const float*)d_in[8];
    const float* linb  = (const float*)d_in[9];
    float* out = (float*)d_out;

    const int* src = eidx;
    const int* dst = eidx + N_EDGES;

    char* p = (char*)d_ws;
    auto alloc = [&](size_t bytes) { char* r = p; p += (bytes + 255) & ~(size_t)255; return r; };
    unsigned short* Xb   = (unsigned short*)alloc((size_t)N_NODES * HDIM * 2);
    unsigned short* HbA  = (unsigned short*)alloc((size_t)N_NODES * HDIM * 2);
    unsigned short* HbB  = (unsigned short*)alloc((size_t)N_NODES * HDIM * 2);
    unsigned short* Wtb  = (unsigned short*)alloc((size_t)NLAYER * 2 * HDIM * HDIM * 2);
    int* row_off = (int*)alloc((N_NODES + 2) * 4);
    int* deg     = (int*)alloc(N_NODES * 4);
    int* cursor  = (int*)alloc(N_NODES * 4);
    int* col     = (int*)alloc((size_t)N_EDGES * 4);
    int* part    = (int*)alloc(SCAN_NB * 4);
    int* gb      = (int*)alloc((NGRAPH + 2) * 4);
    float* pstat = (float*)alloc((size_t)NBLK_G * 256 * 4);
    float* red32 = (float*)alloc(32 * 256 * 4);
    float* scsh  = (float*)alloc(2 * HDIM * 4);
    float* ppart = (float*)alloc((size_t)NGRAPH * POOL_SPLIT * HDIM * 4);
    float* pooled= (float*)alloc(NGRAPH * HDIM * 4);

    // ---- CSR build (XCD-bucketed, nt streams) ----
    hipMemsetAsync(deg, 0, N_NODES * sizeof(int), stream);
    hipMemsetAsync(cursor, 0, N_NODES * sizeof(int), stream);
    k_deg_b<<<1024, 256, 0, stream>>>(dst, deg);
    k_blocksum<<<SCAN_NB, 256, 0, stream>>>(deg, part);
    k_scanpart<<<1, 64, 0, stream>>>(part);
    k_scan2<<<SCAN_NB, 256, 0, stream>>>(deg, part, row_off);
    k_fill_b<<<1024, 256, 0, stream>>>(src, dst, row_off, cursor, col);

    // ---- one-time converts ----
    k_cvt_x<<<N_NODES * HDIM / 4 / 256, 256, 0, stream>>>(x, Xb);
    k_cvt_w<<<NLAYER * 2 * HDIM * HDIM / 256, 256, 0, stream>>>(Wl, Wr, Wtb);
    k_gbound<<<3, 64, 0, stream>>>(batch, gb);

    // ---- layer 0 (no BN on inputs) ----
    k_fused<false><<<NBLK_G, 512, 0, stream>>>(Xb, scsh, row_off, col, Wtb, bl, HbA, pstat);
    k_red1<<<32, 256, 0, stream>>>(pstat, red32);
    k_stats_final<<<1, 128, 0, stream>>>(red32, gamma, beta, scsh);

    // ---- layers 1..5 ----
    unsigned short* Hcur = HbA;
    for (int l = 1; l < NLAYER; ++l) {
        unsigned short* Hout = (l & 1) ? HbB : HbA;
        k_fused<true><<<NBLK_G, 512, 0, stream>>>(
            Hcur, scsh, row_off, col, Wtb + (size_t)l * 2 * HDIM * HDIM,
            bl + (size_t)l * HDIM, Hout, pstat);
        k_red1<<<32, 256, 0, stream>>>(pstat, red32);
        k_stats_final<<<1, 128, 0, stream>>>(red32, gamma + (size_t)l * HDIM,
                                             beta + (size_t)l * HDIM, scsh);
        Hcur = Hout;
    }

    // ---- pool + classifier ----
    k_pool_part<<<dim3(NGRAPH, POOL_SPLIT), 128, 0, stream>>>(Hcur, scsh, gb, ppart);
    k_pool_final<<<NGRAPH, 128, 0, stream>>>(gb, ppart, pooled);
    k_lin<<<NGRAPH, 128, 0, stream>>>(pooled, linW, linb, out);
}

// Round 8
// 735.616 us; speedup vs baseline: 1.4020x; 1.4020x over previous
//
#include <hip/hip_runtime.h>
#include <hip/hip_bf16.h>

#define N_NODES 100000
#define N_EDGES 1600000
#define HDIM    128
#define NLAYER  6
#define NGRAPH  128
#define NCLASS  10
#define BN_EPS  1e-5f

#define POOL_SPLIT 16

#define NBUCK   196          // buckets of 512 nodes (dst >> 9)
#define BSH     9
#define KC_BLOCKS 250
#define KC_CHUNK  6400       // 250 * 6400 = 1.6M edges
#define LCOL_CAP  10240      // bucket edge capacity (mean 8192, 22 sigma margin)

#define GBM 128
#define NBLK_G ((N_NODES + GBM - 1) / GBM)                     // 782

typedef __attribute__((ext_vector_type(8))) short short8v;
typedef __attribute__((ext_vector_type(4))) float f32x4;
typedef __attribute__((ext_vector_type(4))) int int4v;
typedef __attribute__((ext_vector_type(2))) int int2v;

__device__ __forceinline__ float b2f(unsigned short h) {
    return __uint_as_float(((unsigned int)h) << 16);
}
__device__ __forceinline__ unsigned short f2b(float f) {
    unsigned int u = __float_as_uint(f);
    u += 0x7FFF + ((u >> 16) & 1);          // RNE
    return (unsigned short)(u >> 16);
}
__device__ __forceinline__ void gl_lds16(const void* g, void* l) {
    __builtin_amdgcn_global_load_lds((const __attribute__((address_space(1))) unsigned int*)g,
                                     (__attribute__((address_space(3))) unsigned int*)l,
                                     16, 0, 0);
}
__device__ __forceinline__ short8v bn_pack(short8v v, float4 scA, float4 scB,
                                           float4 shA, float4 shB) {
    short8v o;
    o[0] = (short)f2b(fmaxf(0.f, b2f((unsigned short)v[0]) * scA.x + shA.x));
    o[1] = (short)f2b(fmaxf(0.f, b2f((unsigned short)v[1]) * scA.y + shA.y));
    o[2] = (short)f2b(fmaxf(0.f, b2f((unsigned short)v[2]) * scA.z + shA.z));
    o[3] = (short)f2b(fmaxf(0.f, b2f((unsigned short)v[3]) * scA.w + shA.w));
    o[4] = (short)f2b(fmaxf(0.f, b2f((unsigned short)v[4]) * scB.x + shB.x));
    o[5] = (short)f2b(fmaxf(0.f, b2f((unsigned short)v[5]) * scB.y + shB.y));
    o[6] = (short)f2b(fmaxf(0.f, b2f((unsigned short)v[6]) * scB.z + shB.z));
    o[7] = (short)f2b(fmaxf(0.f, b2f((unsigned short)v[7]) * scB.w + shB.w));
    return o;
}

// ---------------- CSR build v3: bucketed 2-pass radix ----------------

__global__ void __launch_bounds__(256) k_hist(const int* __restrict__ dst,
                                              int* __restrict__ bcnt) {
    __shared__ int h[NBUCK];
    for (int i = threadIdx.x; i < NBUCK; i += 256) h[i] = 0;
    __syncthreads();
    const int4v* d4 = (const int4v*)dst;
    int base = blockIdx.x * (KC_CHUNK / 4);
    for (int i = threadIdx.x; i < KC_CHUNK / 4; i += 256) {
        int4v d = __builtin_nontemporal_load(d4 + base + i);
        atomicAdd(&h[d[0] >> BSH], 1);
        atomicAdd(&h[d[1] >> BSH], 1);
        atomicAdd(&h[d[2] >> BSH], 1);
        atomicAdd(&h[d[3] >> BSH], 1);
    }
    __syncthreads();
    for (int i = threadIdx.x; i < NBUCK; i += 256)
        if (h[i]) atomicAdd(&bcnt[i], h[i]);
}

__global__ void k_bscan(const int* __restrict__ bcnt, int* __restrict__ boff,
                        int* __restrict__ bcur, int* __restrict__ row_off) {
    if (threadIdx.x == 0 && blockIdx.x == 0) {
        int acc = 0;
        for (int i = 0; i < NBUCK; ++i) {
            boff[i] = acc; bcur[i] = acc; acc += bcnt[i];
        }
        boff[NBUCK] = acc;               // == N_EDGES
        row_off[N_NODES] = N_EDGES;
    }
}

// partition edges into bucket-contiguous (src,dst) pair runs
__global__ void __launch_bounds__(256) k_part(const int* __restrict__ src,
                                              const int* __restrict__ dst,
                                              int* __restrict__ bcur,
                                              int2v* __restrict__ P) {
    __shared__ int h[NBUCK];      // histogram, then local cursor
    __shared__ int gbase[NBUCK];  // reserved global base
    for (int i = threadIdx.x; i < NBUCK; i += 256) h[i] = 0;
    __syncthreads();
    const int4v* d4 = (const int4v*)dst;
    const int4v* s4 = (const int4v*)src;
    const int base = blockIdx.x * (KC_CHUNK / 4);
    for (int i = threadIdx.x; i < KC_CHUNK / 4; i += 256) {
        int4v d = __builtin_nontemporal_load(d4 + base + i);
        atomicAdd(&h[d[0] >> BSH], 1);
        atomicAdd(&h[d[1] >> BSH], 1);
        atomicAdd(&h[d[2] >> BSH], 1);
        atomicAdd(&h[d[3] >> BSH], 1);
    }
    __syncthreads();
    for (int i = threadIdx.x; i < NBUCK; i += 256) {
        int c = h[i];
        gbase[i] = c ? atomicAdd(&bcur[i], c) : 0;
        h[i] = 0;                 // reuse as local cursor
    }
    __syncthreads();
    for (int i = threadIdx.x; i < KC_CHUNK / 4; i += 256) {
        int4v d = __builtin_nontemporal_load(d4 + base + i);
        int4v s = __builtin_nontemporal_load(s4 + base + i);
#pragma unroll
        for (int k = 0; k < 4; ++k) {
            int b = d[k] >> BSH;
            int pos = gbase[b] + atomicAdd(&h[b], 1);
            int2v pr; pr[0] = s[k]; pr[1] = d[k];
            P[pos] = pr;
        }
    }
}

// per-bucket: build row_off + col with LDS-local scatter, sequential global writes
__global__ void __launch_bounds__(1024) k_bucket(const int2v* __restrict__ P,
                                                 const int* __restrict__ boff,
                                                 int* __restrict__ row_off,
                                                 int* __restrict__ col) {
    __shared__ int ldeg[512];
    __shared__ int lcur[512];
    __shared__ int lcol[LCOL_CAP];
    const int tid = threadIdx.x;
    const int b = blockIdx.x;
    const int pbeg = boff[b], pend = boff[b + 1];
    const int nE = pend - pbeg;
    const int n0 = b << BSH;
    if (tid < 512) ldeg[tid] = 0;
    __syncthreads();
    for (int i = tid; i < nE; i += 1024) {
        int2v pr = P[pbeg + i];
        atomicAdd(&ldeg[pr[1] - n0], 1);
    }
    __syncthreads();
    int myd = (tid < 512) ? ldeg[tid] : 0;
    // inclusive scan over 512 entries (Hillis-Steele)
    for (int off = 1; off < 512; off <<= 1) {
        int t = 0;
        if (tid < 512 && tid >= off) t = ldeg[tid - off];
        __syncthreads();
        if (tid < 512) ldeg[tid] += t;
        __syncthreads();
    }
    if (tid < 512) {
        int excl = ldeg[tid] - myd;
        lcur[tid] = excl;
        int node = n0 + tid;
        if (node < N_NODES) row_off[node] = pbeg + excl;
    }
    __syncthreads();
    for (int i = tid; i < nE; i += 1024) {
        int2v pr = P[pbeg + i];
        int pos = atomicAdd(&lcur[pr[1] - n0], 1);
        if (pos < LCOL_CAP) lcol[pos] = pr[0];
    }
    __syncthreads();
    for (int i = tid; i < nE; i += 1024) col[pbeg + i] = lcol[i];
}

// ---------------- one-time converts ----------------

__global__ void __launch_bounds__(256) k_cvt_x(const float* __restrict__ x,
                                               unsigned short* __restrict__ Xb) {
    int idx = blockIdx.x * 256 + threadIdx.x;          // < N*H/4
    f32x4 v = __builtin_nontemporal_load(((const f32x4*)x) + idx);
    ushort4 o = { f2b(v[0]), f2b(v[1]), f2b(v[2]), f2b(v[3]) };
    ((ushort4*)Xb)[idx] = o;
}

// Wtb[l][n][kk] (kk<128 -> Wl[l][kk][n], else Wr[l][kk-128][n]), bf16
__global__ void __launch_bounds__(256) k_cvt_w(const float* __restrict__ Wl,
                                               const float* __restrict__ Wr,
                                               unsigned short* __restrict__ Wtb) {
    int idx = blockIdx.x * 256 + threadIdx.x;          // < 6*128*256
    int kk = idx & 255;
    int n  = (idx >> 8) & 127;
    int l  = idx >> 15;
    float v = (kk < HDIM) ? Wl[l * HDIM * HDIM + kk * HDIM + n]
                          : Wr[l * HDIM * HDIM + (kk - HDIM) * HDIM + n];
    Wtb[idx] = f2b(v);
}

// ---------------- aggregation ----------------

// 16 nodes/block, 16 threads/node, ushort8 (16B) per thread; 8-deep unrolled gather
__global__ void __launch_bounds__(256) k_agg(const unsigned short* __restrict__ Xb,
                                             const int* __restrict__ row_off,
                                             const int* __restrict__ col,
                                             unsigned short* __restrict__ AGGb) {
    int node = blockIdx.x * 16 + (threadIdx.x >> 4);
    int t = threadIdx.x & 15;
    int s = row_off[node], e = row_off[node + 1];
    float a[8] = {};
    int p = s;
    for (; p + 8 <= e; p += 8) {
        int nb[8];
#pragma unroll
        for (int j = 0; j < 8; ++j) nb[j] = col[p + j];
        short8v v[8];
#pragma unroll
        for (int j = 0; j < 8; ++j)
            v[j] = *(const short8v*)(Xb + (size_t)nb[j] * HDIM + t * 8);
#pragma unroll
        for (int j = 0; j < 8; ++j)
#pragma unroll
            for (int k = 0; k < 8; ++k) a[k] += b2f((unsigned short)v[j][k]);
    }
    if (p + 4 <= e) {
        int nb[4];
#pragma unroll
        for (int j = 0; j < 4; ++j) nb[j] = col[p + j];
        short8v v[4];
#pragma unroll
        for (int j = 0; j < 4; ++j)
            v[j] = *(const short8v*)(Xb + (size_t)nb[j] * HDIM + t * 8);
#pragma unroll
        for (int j = 0; j < 4; ++j)
#pragma unroll
            for (int k = 0; k < 8; ++k) a[k] += b2f((unsigned short)v[j][k]);
        p += 4;
    }
    for (; p < e; ++p) {
        int n0 = col[p];
        short8v v0 = *(const short8v*)(Xb + (size_t)n0 * HDIM + t * 8);
#pragma unroll
        for (int k = 0; k < 8; ++k) a[k] += b2f((unsigned short)v0[k]);
    }
    float w = (e > s) ? 1.0f / (float)(e - s) : 0.f;
    short8v o;
#pragma unroll
    for (int k = 0; k < 8; ++k) o[k] = (short)f2b(a[k] * w);
    *(short8v*)(AGGb + (size_t)node * HDIM + t * 8) = o;
}

// gather raw H, apply BN(scsh)+ReLU on the fly; 8-deep unrolled
__global__ void __launch_bounds__(256) k_agg_bn(const unsigned short* __restrict__ Hb,
                                                const float* __restrict__ scsh,
                                                const int* __restrict__ row_off,
                                                const int* __restrict__ col,
                                                unsigned short* __restrict__ AGGb) {
    int node = blockIdx.x * 16 + (threadIdx.x >> 4);
    int t = threadIdx.x & 15;
    int c8 = t * 8;
    float sc[8], sh[8];
#pragma unroll
    for (int k = 0; k < 8; ++k) { sc[k] = scsh[c8 + k]; sh[k] = scsh[HDIM + c8 + k]; }
    int s = row_off[node], e = row_off[node + 1];
    float a[8] = {};
    int p = s;
    for (; p + 8 <= e; p += 8) {
        int nb[8];
#pragma unroll
        for (int j = 0; j < 8; ++j) nb[j] = col[p + j];
        short8v v[8];
#pragma unroll
        for (int j = 0; j < 8; ++j)
            v[j] = *(const short8v*)(Hb + (size_t)nb[j] * HDIM + c8);
#pragma unroll
        for (int j = 0; j < 8; ++j)
#pragma unroll
            for (int k = 0; k < 8; ++k)
                a[k] += fmaxf(0.f, b2f((unsigned short)v[j][k]) * sc[k] + sh[k]);
    }
    if (p + 4 <= e) {
        int nb[4];
#pragma unroll
        for (int j = 0; j < 4; ++j) nb[j] = col[p + j];
        short8v v[4];
#pragma unroll
        for (int j = 0; j < 4; ++j)
            v[j] = *(const short8v*)(Hb + (size_t)nb[j] * HDIM + c8);
#pragma unroll
        for (int j = 0; j < 4; ++j)
#pragma unroll
            for (int k = 0; k < 8; ++k)
                a[k] += fmaxf(0.f, b2f((unsigned short)v[j][k]) * sc[k] + sh[k]);
        p += 4;
    }
    for (; p < e; ++p) {
        int n0 = col[p];
        short8v v0 = *(const short8v*)(Hb + (size_t)n0 * HDIM + c8);
#pragma unroll
        for (int k = 0; k < 8; ++k)
            a[k] += fmaxf(0.f, b2f((unsigned short)v0[k]) * sc[k] + sh[k]);
    }
    float w = (e > s) ? 1.0f / (float)(e - s) : 0.f;
    short8v o;
#pragma unroll
    for (int k = 0; k < 8; ++k) o[k] = (short)f2b(a[k] * w);
    *(short8v*)(AGGb + (size_t)node * HDIM + c8) = o;
}

// ---------------- GEMMs (128 rows/block, K=256, dbuf, fused BN stats) ----------------

// layer 0: A = [AGGb | Xb], both gl_lds
__global__ void __launch_bounds__(256) k_gemm_l0(const unsigned short* __restrict__ AGGb,
                                                 const unsigned short* __restrict__ Xb,
                                                 const unsigned short* __restrict__ Wtb,
                                                 const float* __restrict__ bl,
                                                 unsigned short* __restrict__ Hb,
                                                 float* __restrict__ pstat) {
    __shared__ __align__(16) char smem[32768];
    const int tid  = threadIdx.x;
    const int bm   = blockIdx.x * GBM;
    const int wv   = tid >> 6;
    const int lane = tid & 63;
    const int li   = lane & 15, hi = lane >> 4;

    f32x4 acc[2][8] = {};

    auto stage = [&](int b, int step) {
        const unsigned short* Asrc = (step < 4) ? AGGb : Xb;
        const int kk0 = (step & 3) * 32;
        char* base = smem + b * 16384;
#pragma unroll
        for (int q = 0; q < 2; ++q) {
            int s = q * 256 + tid;
            int r = s >> 2, sk = s & 3;
            int row = bm + r; if (row >= N_NODES) row = N_NODES - 1;
            gl_lds16((const char*)(Asrc + (size_t)row * HDIM + kk0) + (((sk ^ (r & 3)) & 3) << 4),
                     base + (q * 4 + wv) * 1024);
        }
        const int k0 = step * 32;
#pragma unroll
        for (int q = 0; q < 2; ++q) {
            int s = q * 256 + tid;
            int n = s >> 2, sk = s & 3;
            gl_lds16((const char*)(Wtb + (size_t)n * 256 + k0) + (((sk ^ (n & 3)) & 3) << 4),
                     base + 8192 + (q * 4 + wv) * 1024);
        }
    };

    stage(0, 0);
    __syncthreads();

    int buf = 0;
    for (int step = 0; step < 8; ++step) {
        if (step < 7) stage(buf ^ 1, step + 1);
        char* bA = smem + buf * 16384;
        char* bW = bA + 8192;
        short8v afr[2], bfr[8];
#pragma unroll
        for (int m = 0; m < 2; ++m) {
            int r = wv * 32 + m * 16 + li;
            afr[m] = *(const short8v*)(bA + r * 64 + ((hi ^ (r & 3)) << 4));
        }
#pragma unroll
        for (int nf = 0; nf < 8; ++nf) {
            int n = nf * 16 + li;
            bfr[nf] = *(const short8v*)(bW + n * 64 + ((hi ^ (n & 3)) << 4));
        }
#pragma unroll
        for (int m = 0; m < 2; ++m)
#pragma unroll
            for (int nf = 0; nf < 8; ++nf)
                acc[m][nf] = __builtin_amdgcn_mfma_f32_16x16x32_bf16(afr[m], bfr[nf],
                                                                     acc[m][nf], 0, 0, 0);
        __syncthreads();
        buf ^= 1;
    }

    float* st = (float*)smem;
#pragma unroll
    for (int nf = 0; nf < 8; ++nf) {
        int c = nf * 16 + li;
        float bb = bl[c];
        float ls = 0.f, lq = 0.f;
#pragma unroll
        for (int m = 0; m < 2; ++m) {
            int row0 = bm + wv * 32 + m * 16 + hi * 4;
#pragma unroll
            for (int j = 0; j < 4; ++j) {
                int row = row0 + j;
                if (row < N_NODES) {
                    float v = acc[m][nf][j] + bb;
                    Hb[(size_t)row * HDIM + c] = f2b(v);
                    ls += v; lq += v * v;
                }
            }
        }
        ls += __shfl_xor(ls, 16); ls += __shfl_xor(ls, 32);
        lq += __shfl_xor(lq, 16); lq += __shfl_xor(lq, 32);
        if (hi == 0) {
            st[wv * 128 + c] = ls;
            st[512 + wv * 128 + c] = lq;
        }
    }
    __syncthreads();
    if (tid < 128) {
        float s = st[tid] + st[128 + tid] + st[256 + tid] + st[384 + tid];
        pstat[blockIdx.x * 256 + tid] = s;
    } else {
        int c = tid - 128;
        float q = st[512 + c] + st[640 + c] + st[768 + c] + st[896 + c];
        pstat[blockIdx.x * 256 + tid] = q;
    }
}

// layers 1..5: A = [AGGb | bn_relu(Hprev)] — second half reg-staged with transform
__global__ void __launch_bounds__(256) k_gemm_fuse(const unsigned short* __restrict__ AGGb,
                                                   const unsigned short* __restrict__ Hprev,
                                                   const float* __restrict__ scsh,
                                                   const unsigned short* __restrict__ Wtb,
                                                   const float* __restrict__ bl,
                                                   unsigned short* __restrict__ Hb,
                                                   float* __restrict__ pstat) {
    __shared__ __align__(16) char smem[32768];
    const int tid  = threadIdx.x;
    const int bm   = blockIdx.x * GBM;
    const int wv   = tid >> 6;
    const int lane = tid & 63;
    const int li   = lane & 15, hi = lane >> 4;
    const int rr   = tid >> 2;            // 0..63
    const int sk   = tid & 3;
    const int swz  = ((sk ^ (rr & 3)) << 4);   // r&3 identical for r=rr and r=rr+64

    f32x4 acc[2][8] = {};

    auto stageW = [&](char* base, int step) {
        const int k0 = step * 32;
#pragma unroll
        for (int q = 0; q < 2; ++q) {
            int n = q * 64 + rr;
            gl_lds16((const char*)(Wtb + (size_t)n * 256 + k0) + swz,
                     base + 8192 + (q * 4 + wv) * 1024);
        }
    };
    auto stageA = [&](char* base, int step) {     // AGGb, steps 0..3
        const int kk0 = step * 32;
#pragma unroll
        for (int q = 0; q < 2; ++q) {
            int r = q * 64 + rr;
            int row = bm + r; if (row >= N_NODES) row = N_NODES - 1;
            gl_lds16((const char*)(AGGb + (size_t)row * HDIM + kk0) + swz,
                     base + (q * 4 + wv) * 1024);
        }
    };

    stageA(smem, 0); stageW(smem, 0);
    __syncthreads();

    int buf = 0;
    for (int step = 0; step < 8; ++step) {
        char* cur = smem + buf * 16384;
        char* nxt = smem + (buf ^ 1) * 16384;
        const int ns = step + 1;
        short8v rv0, rv1;
        int c0 = 0;
        bool regstage = false;
        if (step < 7) {
            stageW(nxt, ns);
            if (ns < 4) {
                stageA(nxt, ns);
            } else {
                regstage = true;
                c0 = ns * 32 - 128 + sk * 8;
                int row0 = bm + rr;      if (row0 >= N_NODES) row0 = N_NODES - 1;
                int row1 = bm + 64 + rr; if (row1 >= N_NODES) row1 = N_NODES - 1;
                rv0 = *(const short8v*)(Hprev + (size_t)row0 * HDIM + c0);
                rv1 = *(const short8v*)(Hprev + (size_t)row1 * HDIM + c0);
            }
        }

        short8v afr[2], bfr[8];
#pragma unroll
        for (int m = 0; m < 2; ++m) {
            int r = wv * 32 + m * 16 + li;
            afr[m] = *(const short8v*)(cur + r * 64 + ((hi ^ (r & 3)) << 4));
        }
#pragma unroll
        for (int nf = 0; nf < 8; ++nf) {
            int n = nf * 16 + li;
            bfr[nf] = *(const short8v*)(cur + 8192 + n * 64 + ((hi ^ (n & 3)) << 4));
        }
#pragma unroll
        for (int m = 0; m < 2; ++m)
#pragma unroll
            for (int nf = 0; nf < 8; ++nf)
                acc[m][nf] = __builtin_amdgcn_mfma_f32_16x16x32_bf16(afr[m], bfr[nf],
                                                                     acc[m][nf], 0, 0, 0);

        if (regstage) {
            float4 scA = *(const float4*)&scsh[c0];
            float4 scB = *(const float4*)&scsh[c0 + 4];
            float4 shA = *(const float4*)&scsh[HDIM + c0];
            float4 shB = *(const float4*)&scsh[HDIM + c0 + 4];
            *(short8v*)(nxt + rr * 64 + swz)        = bn_pack(rv0, scA, scB, shA, shB);
            *(short8v*)(nxt + (64 + rr) * 64 + swz) = bn_pack(rv1, scA, scB, shA, shB);
        }
        __syncthreads();
        buf ^= 1;
    }

    float* st = (float*)smem;
#pragma unroll
    for (int nf = 0; nf < 8; ++nf) {
        int c = nf * 16 + li;
        float bb = bl[c];
        float ls = 0.f, lq = 0.f;
#pragma unroll
        for (int m = 0; m < 2; ++m) {
            int row0 = bm + wv * 32 + m * 16 + hi * 4;
#pragma unroll
            for (int j = 0; j < 4; ++j) {
                int row = row0 + j;
                if (row < N_NODES) {
                    float v = acc[m][nf][j] + bb;
                    Hb[(size_t)row * HDIM + c] = f2b(v);
                    ls += v; lq += v * v;
                }
            }
        }
        ls += __shfl_xor(ls, 16); ls += __shfl_xor(ls, 32);
        lq += __shfl_xor(lq, 16); lq += __shfl_xor(lq, 32);
        if (hi == 0) {
            st[wv * 128 + c] = ls;
            st[512 + wv * 128 + c] = lq;
        }
    }
    __syncthreads();
    if (tid < 128) {
        float s = st[tid] + st[128 + tid] + st[256 + tid] + st[384 + tid];
        pstat[blockIdx.x * 256 + tid] = s;
    } else {
        int c = tid - 128;
        float q = st[512 + c] + st[640 + c] + st[768 + c] + st[896 + c];
        pstat[blockIdx.x * 256 + tid] = q;
    }
}

__global__ void __launch_bounds__(256) k_red1(const float* __restrict__ pstat,
                                              float* __restrict__ red32) {
    int c = threadIdx.x, b = blockIdx.x;
    float s = 0.f;
    for (int r = b; r < NBLK_G; r += 32) s += pstat[r * 256 + c];
    red32[b * 256 + c] = s;
}

__global__ void __launch_bounds__(128) k_stats_final(const float* __restrict__ red32,
                                                     const float* __restrict__ gamma,
                                                     const float* __restrict__ beta,
                                                     float* __restrict__ scsh) {
    int c = threadIdx.x;
    float s = 0.f, q = 0.f;
    for (int r = 0; r < 32; ++r) { s += red32[r * 256 + c]; q += red32[r * 256 + 128 + c]; }
    float mu = s / (float)N_NODES;
    float var = q / (float)N_NODES - mu * mu;
    float rs = rsqrtf(var + BN_EPS);
    float sc = gamma[c] * rs;
    scsh[c] = sc;
    scsh[HDIM + c] = beta[c] - mu * sc;
}

// ---------------- pooling + classifier ----------------

__global__ void k_gbound(const int* __restrict__ batch, int* __restrict__ gb) {
    int t = blockIdx.x * 64 + threadIdx.x;
    if (t > NGRAPH) return;
    int lo = 0, hi = N_NODES;
    while (lo < hi) { int mid = (lo + hi) >> 1; if (batch[mid] < t) lo = mid + 1; else hi = mid; }
    gb[t] = lo;
}

// pool over bn_relu(H_final) applied on the fly
__global__ void __launch_bounds__(128) k_pool_part(const unsigned short* __restrict__ Hb,
                                                   const float* __restrict__ scsh,
                                                   const int* __restrict__ gb,
                                                   float* __restrict__ ppart) {
    int g = blockIdx.x, sp = blockIdx.y;
    int c = threadIdx.x;
    float sc = scsh[c], sh = scsh[HDIM + c];
    int s = gb[g], e = gb[g + 1];
    float acc = 0.f;
    for (int i = s + sp; i < e; i += POOL_SPLIT)
        acc += fmaxf(0.f, b2f(Hb[(size_t)i * HDIM + c]) * sc + sh);
    ppart[(g * POOL_SPLIT + sp) * HDIM + c] = acc;
}

__global__ void __launch_bounds__(128) k_pool_final(const int* __restrict__ gb,
                                                    const float* __restrict__ ppart,
                                                    float* __restrict__ pooled) {
    int g = blockIdx.x, c = threadIdx.x;
    float s = 0.f;
    for (int sp = 0; sp < POOL_SPLIT; ++sp) s += ppart[(g * POOL_SPLIT + sp) * HDIM + c];
    int cnt = gb[g + 1] - gb[g]; if (cnt < 1) cnt = 1;
    pooled[g * HDIM + c] = s / (float)cnt;
}

__global__ void __launch_bounds__(128) k_lin(const float* __restrict__ pooled,
                                             const float* __restrict__ W,
                                             const float* __restrict__ bvec,
                                             float* __restrict__ out) {
    __shared__ float p[HDIM];
    int g = blockIdx.x, t = threadIdx.x;
    p[t] = pooled[g * HDIM + t];
    __syncthreads();
    if (t < NCLASS) {
        float acc = bvec[t];
        for (int k = 0; k < HDIM; ++k) acc += p[k] * W[k * NCLASS + t];
        out[g * NCLASS + t] = acc;
    }
}

// ---------------- launch ----------------

extern "C" void kernel_launch(void* const* d_in, const int* in_sizes, int n_in,
                              void* d_out, int out_size, void* d_ws, size_t ws_size,
                              hipStream_t stream) {
    const float* x     = (const float*)d_in[0];
    const int*   eidx  = (const int*)d_in[1];
    const int*   batch = (const int*)d_in[2];
    const float* Wl    = (const float*)d_in[3];
    const float* bl    = (const float*)d_in[4];
    const float* Wr    = (const float*)d_in[5];
    const float* gamma = (const float*)d_in[6];
    const float* beta  = (const float*)d_in[7];
    const float* linW  = (const float*)d_in[8];
    const float* linb  = (const float*)d_in[9];
    float* out = (float*)d_out;

    const int* src = eidx;
    const int* dst = eidx + N_EDGES;

    char* p = (char*)d_ws;
    auto alloc = [&](size_t bytes) { char* r = p; p += (bytes + 255) & ~(size_t)255; return r; };
    unsigned short* Xb   = (unsigned short*)alloc((size_t)N_NODES * HDIM * 2);
    unsigned short* AGGb = (unsigned short*)alloc((size_t)N_NODES * HDIM * 2);
    unsigned short* HbA  = (unsigned short*)alloc((size_t)N_NODES * HDIM * 2);
    unsigned short* HbB  = (unsigned short*)alloc((size_t)N_NODES * HDIM * 2);
    unsigned short* Wtb  = (unsigned short*)alloc((size_t)NLAYER * 2 * HDIM * HDIM * 2);
    int*   row_off = (int*)alloc((N_NODES + 2) * 4);
    int*   col     = (int*)alloc((size_t)N_EDGES * 4);
    int2v* P       = (int2v*)alloc((size_t)N_EDGES * 8);
    int*   bcnt    = (int*)alloc(NBUCK * 4);
    int*   boff    = (int*)alloc((NBUCK + 1) * 4);
    int*   bcur    = (int*)alloc(NBUCK * 4);
    int*   gb      = (int*)alloc((NGRAPH + 2) * 4);
    float* pstat   = (float*)alloc((size_t)NBLK_G * 256 * 4);
    float* red32   = (float*)alloc(32 * 256 * 4);
    float* scsh    = (float*)alloc(2 * HDIM * 4);
    float* ppart   = (float*)alloc((size_t)NGRAPH * POOL_SPLIT * HDIM * 4);
    float* pooled  = (float*)alloc(NGRAPH * HDIM * 4);

    // ---- CSR build v3 ----
    hipMemsetAsync(bcnt, 0, NBUCK * sizeof(int), stream);
    k_hist<<<KC_BLOCKS, 256, 0, stream>>>(dst, bcnt);
    k_bscan<<<1, 64, 0, stream>>>(bcnt, boff, bcur, row_off);
    k_part<<<KC_BLOCKS, 256, 0, stream>>>(src, dst, bcur, P);
    k_bucket<<<NBUCK, 1024, 0, stream>>>(P, boff, row_off, col);

    // ---- one-time converts ----
    k_cvt_x<<<N_NODES * HDIM / 4 / 256, 256, 0, stream>>>(x, Xb);
    k_cvt_w<<<NLAYER * 2 * HDIM * HDIM / 256, 256, 0, stream>>>(Wl, Wr, Wtb);
    k_gbound<<<3, 64, 0, stream>>>(batch, gb);

    // ---- layer 0 ----
    k_agg<<<N_NODES / 16, 256, 0, stream>>>(Xb, row_off, col, AGGb);
    k_gemm_l0<<<NBLK_G, 256, 0, stream>>>(AGGb, Xb, Wtb, bl, HbA, pstat);
    k_red1<<<32, 256, 0, stream>>>(pstat, red32);
    k_stats_final<<<1, 128, 0, stream>>>(red32, gamma, beta, scsh);

    // ---- layers 1..5 ----
    unsigned short* Hcur = HbA;
    for (int l = 1; l < NLAYER; ++l) {
        unsigned short* Hout = (l & 1) ? HbB : HbA;
        k_agg_bn<<<N_NODES / 16, 256, 0, stream>>>(Hcur, scsh, row_off, col, AGGb);
        k_gemm_fuse<<<NBLK_G, 256, 0, stream>>>(
            AGGb, Hcur, scsh, Wtb + (size_t)l * 2 * HDIM * HDIM, bl + (size_t)l * HDIM,
            Hout, pstat);
        k_red1<<<32, 256, 0, stream>>>(pstat, red32);
        k_stats_final<<<1, 128, 0, stream>>>(red32, gamma + (size_t)l * HDIM,
                                             beta + (size_t)l * HDIM, scsh);
        Hcur = Hout;
    }

    // ---- pool + classifier ----
    k_pool_part<<<dim3(NGRAPH, POOL_SPLIT), 128, 0, stream>>>(Hcur, scsh, gb, ppart);
    k_pool_final<<<NGRAPH, 128, 0, stream>>>(gb, ppart, pooled);
    k_lin<<<NGRAPH, 128, 0, stream>>>(pooled, linW, linb, out);
}

// Round 9
// 710.918 us; speedup vs baseline: 1.4507x; 1.0347x over previous
//
#include <hip/hip_runtime.h>
#include <hip/hip_bf16.h>

#define N_NODES 100000
#define N_EDGES 1600000
#define HDIM    128
#define NLAYER  6
#define NGRAPH  128
#define NCLASS  10
#define BN_EPS  1e-5f

#define POOL_SPLIT 16

#define NBUCK   196          // buckets of 512 nodes (dst >> 9)
#define BSH     9
#define KC_BLOCKS 250
#define KC_CHUNK  6400       // 250 * 6400 = 1.6M edges
#define LCOL_CAP  10240

#define GBM 256
#define NBLK_G ((N_NODES + GBM - 1) / GBM)                     // 391

typedef __attribute__((ext_vector_type(8))) short short8v;
typedef __attribute__((ext_vector_type(4))) float f32x4;
typedef __attribute__((ext_vector_type(2))) float f32x2;
typedef __attribute__((ext_vector_type(4))) int int4v;
typedef __attribute__((ext_vector_type(2))) int int2v;

__device__ __forceinline__ float b2f(unsigned short h) {
    return __uint_as_float(((unsigned int)h) << 16);
}
__device__ __forceinline__ unsigned short f2b(float f) {
    unsigned int u = __float_as_uint(f);
    u += 0x7FFF + ((u >> 16) & 1);          // RNE
    return (unsigned short)(u >> 16);
}
__device__ __forceinline__ void gl_lds16(const void* g, void* l) {
    __builtin_amdgcn_global_load_lds((const __attribute__((address_space(1))) unsigned int*)g,
                                     (__attribute__((address_space(3))) unsigned int*)l,
                                     16, 0, 0);
}
__device__ __forceinline__ short8v bn_pack(short8v v, float4 scA, float4 scB,
                                           float4 shA, float4 shB) {
    short8v o;
    o[0] = (short)f2b(fmaxf(0.f, b2f((unsigned short)v[0]) * scA.x + shA.x));
    o[1] = (short)f2b(fmaxf(0.f, b2f((unsigned short)v[1]) * scA.y + shA.y));
    o[2] = (short)f2b(fmaxf(0.f, b2f((unsigned short)v[2]) * scA.z + shA.z));
    o[3] = (short)f2b(fmaxf(0.f, b2f((unsigned short)v[3]) * scA.w + shA.w));
    o[4] = (short)f2b(fmaxf(0.f, b2f((unsigned short)v[4]) * scB.x + shB.x));
    o[5] = (short)f2b(fmaxf(0.f, b2f((unsigned short)v[5]) * scB.y + shB.y));
    o[6] = (short)f2b(fmaxf(0.f, b2f((unsigned short)v[6]) * scB.z + shB.z));
    o[7] = (short)f2b(fmaxf(0.f, b2f((unsigned short)v[7]) * scB.w + shB.w));
    return o;
}

// ---------------- CSR build v3: bucketed 2-pass radix ----------------

__global__ void __launch_bounds__(256) k_hist(const int* __restrict__ dst,
                                              int* __restrict__ bcnt) {
    __shared__ int h[NBUCK];
    for (int i = threadIdx.x; i < NBUCK; i += 256) h[i] = 0;
    __syncthreads();
    const int4v* d4 = (const int4v*)dst;
    int base = blockIdx.x * (KC_CHUNK / 4);
    for (int i = threadIdx.x; i < KC_CHUNK / 4; i += 256) {
        int4v d = __builtin_nontemporal_load(d4 + base + i);
        atomicAdd(&h[d[0] >> BSH], 1);
        atomicAdd(&h[d[1] >> BSH], 1);
        atomicAdd(&h[d[2] >> BSH], 1);
        atomicAdd(&h[d[3] >> BSH], 1);
    }
    __syncthreads();
    for (int i = threadIdx.x; i < NBUCK; i += 256)
        if (h[i]) atomicAdd(&bcnt[i], h[i]);
}

__global__ void k_bscan(const int* __restrict__ bcnt, int* __restrict__ boff,
                        int* __restrict__ bcur, int* __restrict__ row_off) {
    if (threadIdx.x == 0 && blockIdx.x == 0) {
        int acc = 0;
        for (int i = 0; i < NBUCK; ++i) {
            boff[i] = acc; bcur[i] = acc; acc += bcnt[i];
        }
        boff[NBUCK] = acc;
        row_off[N_NODES] = N_EDGES;
    }
}

__global__ void __launch_bounds__(256) k_part(const int* __restrict__ src,
                                              const int* __restrict__ dst,
                                              int* __restrict__ bcur,
                                              int2v* __restrict__ P) {
    __shared__ int h[NBUCK];
    __shared__ int gbase[NBUCK];
    for (int i = threadIdx.x; i < NBUCK; i += 256) h[i] = 0;
    __syncthreads();
    const int4v* d4 = (const int4v*)dst;
    const int4v* s4 = (const int4v*)src;
    const int base = blockIdx.x * (KC_CHUNK / 4);
    for (int i = threadIdx.x; i < KC_CHUNK / 4; i += 256) {
        int4v d = __builtin_nontemporal_load(d4 + base + i);
        atomicAdd(&h[d[0] >> BSH], 1);
        atomicAdd(&h[d[1] >> BSH], 1);
        atomicAdd(&h[d[2] >> BSH], 1);
        atomicAdd(&h[d[3] >> BSH], 1);
    }
    __syncthreads();
    for (int i = threadIdx.x; i < NBUCK; i += 256) {
        int c = h[i];
        gbase[i] = c ? atomicAdd(&bcur[i], c) : 0;
        h[i] = 0;
    }
    __syncthreads();
    for (int i = threadIdx.x; i < KC_CHUNK / 4; i += 256) {
        int4v d = __builtin_nontemporal_load(d4 + base + i);
        int4v s = __builtin_nontemporal_load(s4 + base + i);
#pragma unroll
        for (int k = 0; k < 4; ++k) {
            int b = d[k] >> BSH;
            int pos = gbase[b] + atomicAdd(&h[b], 1);
            int2v pr; pr[0] = s[k]; pr[1] = d[k];
            P[pos] = pr;
        }
    }
}

__global__ void __launch_bounds__(1024) k_bucket(const int2v* __restrict__ P,
                                                 const int* __restrict__ boff,
                                                 int* __restrict__ row_off,
                                                 int* __restrict__ col) {
    __shared__ int ldeg[512];
    __shared__ int lcur[512];
    __shared__ int lcol[LCOL_CAP];
    const int tid = threadIdx.x;
    const int b = blockIdx.x;
    const int pbeg = boff[b], pend = boff[b + 1];
    const int nE = pend - pbeg;
    const int n0 = b << BSH;
    if (tid < 512) ldeg[tid] = 0;
    __syncthreads();
    for (int i = tid; i < nE; i += 1024) {
        int2v pr = P[pbeg + i];
        atomicAdd(&ldeg[pr[1] - n0], 1);
    }
    __syncthreads();
    int myd = (tid < 512) ? ldeg[tid] : 0;
    for (int off = 1; off < 512; off <<= 1) {
        int t = 0;
        if (tid < 512 && tid >= off) t = ldeg[tid - off];
        __syncthreads();
        if (tid < 512) ldeg[tid] += t;
        __syncthreads();
    }
    if (tid < 512) {
        int excl = ldeg[tid] - myd;
        lcur[tid] = excl;
        int node = n0 + tid;
        if (node < N_NODES) row_off[node] = pbeg + excl;
    }
    __syncthreads();
    for (int i = tid; i < nE; i += 1024) {
        int2v pr = P[pbeg + i];
        int pos = atomicAdd(&lcur[pr[1] - n0], 1);
        if (pos < LCOL_CAP) lcol[pos] = pr[0];
    }
    __syncthreads();
    for (int i = tid; i < nE; i += 1024) col[pbeg + i] = lcol[i];
}

// ---------------- one-time converts ----------------

__global__ void __launch_bounds__(256) k_cvt_x(const float* __restrict__ x,
                                               unsigned short* __restrict__ Xb) {
    int idx = blockIdx.x * 256 + threadIdx.x;
    f32x4 v = __builtin_nontemporal_load(((const f32x4*)x) + idx);
    ushort4 o = { f2b(v[0]), f2b(v[1]), f2b(v[2]), f2b(v[3]) };
    ((ushort4*)Xb)[idx] = o;
}

__global__ void __launch_bounds__(256) k_cvt_w(const float* __restrict__ Wl,
                                               const float* __restrict__ Wr,
                                               unsigned short* __restrict__ Wtb) {
    int idx = blockIdx.x * 256 + threadIdx.x;
    int kk = idx & 255;
    int n  = (idx >> 8) & 127;
    int l  = idx >> 15;
    float v = (kk < HDIM) ? Wl[l * HDIM * HDIM + kk * HDIM + n]
                          : Wr[l * HDIM * HDIM + (kk - HDIM) * HDIM + n];
    Wtb[idx] = f2b(v);
}

// ---------------- aggregation v3: LDS col staging + packed f32x2 math ----------------
// 16 nodes/block (contiguous edge range thanks to bucketed CSR), 16 threads/node.
template<bool BN>
__global__ void __launch_bounds__(256) k_aggk(const unsigned short* __restrict__ Hb,
                                              const float* __restrict__ scsh,
                                              const int* __restrict__ row_off,
                                              const int* __restrict__ col,
                                              unsigned short* __restrict__ AGGb) {
    __shared__ int lcol[2048];
    __shared__ int sro[17];
    const int tid = threadIdx.x;
    const int nb0 = blockIdx.x * 16;
    if (tid <= 16) sro[tid] = row_off[nb0 + tid];
    __syncthreads();
    const int s0 = sro[0];
    const int nE = sro[16] - s0;
    const bool fits = (nE <= 2048);
    if (fits) {
        for (int i = tid; i < nE; i += 256) lcol[i] = col[s0 + i];
    }
    __syncthreads();

    const int g  = tid >> 4;
    const int t  = tid & 15;
    const int c8 = t * 8;
    f32x2 sc2[4], sh2[4];
    if (BN) {
#pragma unroll
        for (int q = 0; q < 4; ++q) {
            sc2[q][0] = scsh[c8 + 2 * q];     sc2[q][1] = scsh[c8 + 2 * q + 1];
            sh2[q][0] = scsh[HDIM + c8 + 2 * q]; sh2[q][1] = scsh[HDIM + c8 + 2 * q + 1];
        }
    }
    const int s = sro[g] - s0, e = sro[g + 1] - s0;
    const int* cp = fits ? lcol : (col + s0);
    const f32x2 zero2 = {0.f, 0.f};
    f32x2 a2[4] = {};

    auto accum = [&](int4v v) {
#pragma unroll
        for (int q = 0; q < 4; ++q) {
            unsigned w = (unsigned)v[q];
            f32x2 x;
            x[0] = __uint_as_float(w << 16);
            x[1] = __uint_as_float(w & 0xffff0000u);
            if (BN) {
                x = __builtin_elementwise_fma(x, sc2[q], sh2[q]);
                x = __builtin_elementwise_max(x, zero2);
            }
            a2[q] += x;
        }
    };

    int p = s;
    for (; p + 8 <= e; p += 8) {
        int nbx[8];
#pragma unroll
        for (int j = 0; j < 8; ++j) nbx[j] = cp[p + j];
        int4v v[8];
#pragma unroll
        for (int j = 0; j < 8; ++j)
            v[j] = *(const int4v*)(Hb + (size_t)nbx[j] * HDIM + c8);
#pragma unroll
        for (int j = 0; j < 8; ++j) accum(v[j]);
    }
    if (p + 4 <= e) {
        int nbx[4];
#pragma unroll
        for (int j = 0; j < 4; ++j) nbx[j] = cp[p + j];
        int4v v[4];
#pragma unroll
        for (int j = 0; j < 4; ++j)
            v[j] = *(const int4v*)(Hb + (size_t)nbx[j] * HDIM + c8);
#pragma unroll
        for (int j = 0; j < 4; ++j) accum(v[j]);
        p += 4;
    }
    for (; p < e; ++p) {
        int4v v0 = *(const int4v*)(Hb + (size_t)cp[p] * HDIM + c8);
        accum(v0);
    }
    float w = (e > s) ? 1.0f / (float)(e - s) : 0.f;
    short8v o;
#pragma unroll
    for (int q = 0; q < 4; ++q) {
        o[2 * q]     = (short)f2b(a2[q][0] * w);
        o[2 * q + 1] = (short)f2b(a2[q][1] * w);
    }
    *(short8v*)(AGGb + (size_t)(nb0 + g) * HDIM + c8) = o;
}

// ---------------- GEMMs (256 rows/block, 512 thr, K=256, dbuf, fused BN stats) ----------------
// LDS: A dbuf 2x16KB @0, W dbuf 2x8KB @32768 (48KB). Invariant: LDS[r][j^(r&3)] = G[r][j].

__global__ void __launch_bounds__(512) k_gemm_l0(const unsigned short* __restrict__ AGGb,
                                                 const unsigned short* __restrict__ Xb,
                                                 const unsigned short* __restrict__ Wtb,
                                                 const float* __restrict__ bl,
                                                 unsigned short* __restrict__ Hb,
                                                 float* __restrict__ pstat) {
    __shared__ __align__(16) char smem[49152];
    const int tid  = threadIdx.x;
    const int bm   = blockIdx.x * GBM;
    const int wv   = tid >> 6;          // 0..7
    const int lane = tid & 63;
    const int li   = lane & 15, hi = lane >> 4;

    f32x4 acc[2][8] = {};

    auto stage = [&](int b, int step) {
        const unsigned short* Asrc = (step < 4) ? AGGb : Xb;
        const int kk0 = (step & 3) * 32;
        char* baseA = smem + b * 16384;
        const int sk = tid & 3;
#pragma unroll
        for (int q = 0; q < 2; ++q) {
            int r = q * 128 + (tid >> 2);
            int row = bm + r; if (row >= N_NODES) row = N_NODES - 1;
            gl_lds16((const char*)(Asrc + (size_t)row * HDIM + kk0) + (((sk ^ (r & 3)) & 3) << 4),
                     baseA + (q * 8 + wv) * 1024);
        }
        const int k0 = step * 32;
        {
            int n = tid >> 2;
            gl_lds16((const char*)(Wtb + (size_t)n * 256 + k0) + (((sk ^ (n & 3)) & 3) << 4),
                     smem + 32768 + b * 8192 + wv * 1024);
        }
    };

    stage(0, 0);
    __syncthreads();

    int buf = 0;
    for (int step = 0; step < 8; ++step) {
        if (step < 7) stage(buf ^ 1, step + 1);
        char* bA = smem + buf * 16384;
        char* bW = smem + 32768 + buf * 8192;
        short8v afr[2], bfr[8];
#pragma unroll
        for (int m = 0; m < 2; ++m) {
            int r = wv * 32 + m * 16 + li;
            afr[m] = *(const short8v*)(bA + r * 64 + ((hi ^ (r & 3)) << 4));
        }
#pragma unroll
        for (int nf = 0; nf < 8; ++nf) {
            int n = nf * 16 + li;
            bfr[nf] = *(const short8v*)(bW + n * 64 + ((hi ^ (n & 3)) << 4));
        }
#pragma unroll
        for (int m = 0; m < 2; ++m)
#pragma unroll
            for (int nf = 0; nf < 8; ++nf)
                acc[m][nf] = __builtin_amdgcn_mfma_f32_16x16x32_bf16(afr[m], bfr[nf],
                                                                     acc[m][nf], 0, 0, 0);
        __syncthreads();
        buf ^= 1;
    }

    float* st = (float*)smem;   // [0,1024) sums, [1024,2048) sqs
#pragma unroll
    for (int nf = 0; nf < 8; ++nf) {
        int c = nf * 16 + li;
        float bb = bl[c];
        float ls = 0.f, lq = 0.f;
#pragma unroll
        for (int m = 0; m < 2; ++m) {
            int row0 = bm + wv * 32 + m * 16 + hi * 4;
#pragma unroll
            for (int j = 0; j < 4; ++j) {
                int row = row0 + j;
                if (row < N_NODES) {
                    float v = acc[m][nf][j] + bb;
                    Hb[(size_t)row * HDIM + c] = f2b(v);
                    ls += v; lq += v * v;
                }
            }
        }
        ls += __shfl_xor(ls, 16); ls += __shfl_xor(ls, 32);
        lq += __shfl_xor(lq, 16); lq += __shfl_xor(lq, 32);
        if (hi == 0) {
            st[wv * 128 + c] = ls;
            st[1024 + wv * 128 + c] = lq;
        }
    }
    __syncthreads();
    if (tid < 128) {
        float s = 0.f;
#pragma unroll
        for (int w8 = 0; w8 < 8; ++w8) s += st[w8 * 128 + tid];
        pstat[blockIdx.x * 256 + tid] = s;
    } else if (tid < 256) {
        int c = tid - 128;
        float q = 0.f;
#pragma unroll
        for (int w8 = 0; w8 < 8; ++w8) q += st[1024 + w8 * 128 + c];
        pstat[blockIdx.x * 256 + tid] = q;
    }
}

__global__ void __launch_bounds__(512) k_gemm_fuse(const unsigned short* __restrict__ AGGb,
                                                   const unsigned short* __restrict__ Hprev,
                                                   const float* __restrict__ scsh,
                                                   const unsigned short* __restrict__ Wtb,
                                                   const float* __restrict__ bl,
                                                   unsigned short* __restrict__ Hb,
                                                   float* __restrict__ pstat) {
    __shared__ __align__(16) char smem[49152];
    const int tid  = threadIdx.x;
    const int bm   = blockIdx.x * GBM;
    const int wv   = tid >> 6;
    const int lane = tid & 63;
    const int li   = lane & 15, hi = lane >> 4;
    const int rr   = tid >> 2;            // 0..127
    const int sk   = tid & 3;
    const int swz  = ((sk ^ (rr & 3)) << 4);   // rr&3 == (128+rr)&3

    f32x4 acc[2][8] = {};

    auto stageW = [&](int b, int step) {
        const int k0 = step * 32;
        gl_lds16((const char*)(Wtb + (size_t)rr * 256 + k0) + swz,
                 smem + 32768 + b * 8192 + wv * 1024);
    };
    auto stageA = [&](int b, int step) {     // AGGb, steps 0..3
        const int kk0 = step * 32;
        char* baseA = smem + b * 16384;
#pragma unroll
        for (int q = 0; q < 2; ++q) {
            int r = q * 128 + rr;
            int row = bm + r; if (row >= N_NODES) row = N_NODES - 1;
            gl_lds16((const char*)(AGGb + (size_t)row * HDIM + kk0) + swz,
                     baseA + (q * 8 + wv) * 1024);
        }
    };

    stageA(0, 0); stageW(0, 0);
    __syncthreads();

    int buf = 0;
    for (int step = 0; step < 8; ++step) {
        char* curA = smem + buf * 16384;
        char* curW = smem + 32768 + buf * 8192;
        char* nxtA = smem + (buf ^ 1) * 16384;
        const int ns = step + 1;
        short8v rv0, rv1;
        int c0 = 0;
        bool regstage = false;
        if (step < 7) {
            stageW(buf ^ 1, ns);
            if (ns < 4) {
                stageA(buf ^ 1, ns);
            } else {
                regstage = true;
                c0 = (ns - 4) * 32 + sk * 8;
                int row0 = bm + rr;       if (row0 >= N_NODES) row0 = N_NODES - 1;
                int row1 = bm + 128 + rr; if (row1 >= N_NODES) row1 = N_NODES - 1;
                rv0 = *(const short8v*)(Hprev + (size_t)row0 * HDIM + c0);
                rv1 = *(const short8v*)(Hprev + (size_t)row1 * HDIM + c0);
            }
        }

        short8v afr[2], bfr[8];
#pragma unroll
        for (int m = 0; m < 2; ++m) {
            int r = wv * 32 + m * 16 + li;
            afr[m] = *(const short8v*)(curA + r * 64 + ((hi ^ (r & 3)) << 4));
        }
#pragma unroll
        for (int nf = 0; nf < 8; ++nf) {
            int n = nf * 16 + li;
            bfr[nf] = *(const short8v*)(curW + n * 64 + ((hi ^ (n & 3)) << 4));
        }
#pragma unroll
        for (int m = 0; m < 2; ++m)
#pragma unroll
            for (int nf = 0; nf < 8; ++nf)
                acc[m][nf] = __builtin_amdgcn_mfma_f32_16x16x32_bf16(afr[m], bfr[nf],
                                                                     acc[m][nf], 0, 0, 0);

        if (regstage) {
            float4 scA = *(const float4*)&scsh[c0];
            float4 scB = *(const float4*)&scsh[c0 + 4];
            float4 shA = *(const float4*)&scsh[HDIM + c0];
            float4 shB = *(const float4*)&scsh[HDIM + c0 + 4];
            *(short8v*)(nxtA + rr * 64 + swz)         = bn_pack(rv0, scA, scB, shA, shB);
            *(short8v*)(nxtA + (128 + rr) * 64 + swz) = bn_pack(rv1, scA, scB, shA, shB);
        }
        __syncthreads();
        buf ^= 1;
    }

    float* st = (float*)smem;
#pragma unroll
    for (int nf = 0; nf < 8; ++nf) {
        int c = nf * 16 + li;
        float bb = bl[c];
        float ls = 0.f, lq = 0.f;
#pragma unroll
        for (int m = 0; m < 2; ++m) {
            int row0 = bm + wv * 32 + m * 16 + hi * 4;
#pragma unroll
            for (int j = 0; j < 4; ++j) {
                int row = row0 + j;
                if (row < N_NODES) {
                    float v = acc[m][nf][j] + bb;
                    Hb[(size_t)row * HDIM + c] = f2b(v);
                    ls += v; lq += v * v;
                }
            }
        }
        ls += __shfl_xor(ls, 16); ls += __shfl_xor(ls, 32);
        lq += __shfl_xor(lq, 16); lq += __shfl_xor(lq, 32);
        if (hi == 0) {
            st[wv * 128 + c] = ls;
            st[1024 + wv * 128 + c] = lq;
        }
    }
    __syncthreads();
    if (tid < 128) {
        float s = 0.f;
#pragma unroll
        for (int w8 = 0; w8 < 8; ++w8) s += st[w8 * 128 + tid];
        pstat[blockIdx.x * 256 + tid] = s;
    } else if (tid < 256) {
        int c = tid - 128;
        float q = 0.f;
#pragma unroll
        for (int w8 = 0; w8 < 8; ++w8) q += st[1024 + w8 * 128 + c];
        pstat[blockIdx.x * 256 + tid] = q;
    }
}

__global__ void __launch_bounds__(256) k_red1(const float* __restrict__ pstat,
                                              float* __restrict__ red32) {
    int c = threadIdx.x, b = blockIdx.x;
    float s = 0.f;
    for (int r = b; r < NBLK_G; r += 32) s += pstat[r * 256 + c];
    red32[b * 256 + c] = s;
}

__global__ void __launch_bounds__(128) k_stats_final(const float* __restrict__ red32,
                                                     const float* __restrict__ gamma,
                                                     const float* __restrict__ beta,
                                                     float* __restrict__ scsh) {
    int c = threadIdx.x;
    float s = 0.f, q = 0.f;
    for (int r = 0; r < 32; ++r) { s += red32[r * 256 + c]; q += red32[r * 256 + 128 + c]; }
    float mu = s / (float)N_NODES;
    float var = q / (float)N_NODES - mu * mu;
    float rs = rsqrtf(var + BN_EPS);
    float sc = gamma[c] * rs;
    scsh[c] = sc;
    scsh[HDIM + c] = beta[c] - mu * sc;
}

// ---------------- pooling + classifier ----------------

__global__ void k_gbound(const int* __restrict__ batch, int* __restrict__ gb) {
    int t = blockIdx.x * 64 + threadIdx.x;
    if (t > NGRAPH) return;
    int lo = 0, hi = N_NODES;
    while (lo < hi) { int mid = (lo + hi) >> 1; if (batch[mid] < t) lo = mid + 1; else hi = mid; }
    gb[t] = lo;
}

__global__ void __launch_bounds__(128) k_pool_part(const unsigned short* __restrict__ Hb,
                                                   const float* __restrict__ scsh,
                                                   const int* __restrict__ gb,
                                                   float* __restrict__ ppart) {
    int g = blockIdx.x, sp = blockIdx.y;
    int c = threadIdx.x;
    float sc = scsh[c], sh = scsh[HDIM + c];
    int s = gb[g], e = gb[g + 1];
    float acc = 0.f;
    for (int i = s + sp; i < e; i += POOL_SPLIT)
        acc += fmaxf(0.f, b2f(Hb[(size_t)i * HDIM + c]) * sc + sh);
    ppart[(g * POOL_SPLIT + sp) * HDIM + c] = acc;
}

__global__ void __launch_bounds__(128) k_pool_final(const int* __restrict__ gb,
                                                    const float* __restrict__ ppart,
                                                    float* __restrict__ pooled) {
    int g = blockIdx.x, c = threadIdx.x;
    float s = 0.f;
    for (int sp = 0; sp < POOL_SPLIT; ++sp) s += ppart[(g * POOL_SPLIT + sp) * HDIM + c];
    int cnt = gb[g + 1] - gb[g]; if (cnt < 1) cnt = 1;
    pooled[g * HDIM + c] = s / (float)cnt;
}

__global__ void __launch_bounds__(128) k_lin(const float* __restrict__ pooled,
                                             const float* __restrict__ W,
                                             const float* __restrict__ bvec,
                                             float* __restrict__ out) {
    __shared__ float p[HDIM];
    int g = blockIdx.x, t = threadIdx.x;
    p[t] = pooled[g * HDIM + t];
    __syncthreads();
    if (t < NCLASS) {
        float acc = bvec[t];
        for (int k = 0; k < HDIM; ++k) acc += p[k] * W[k * NCLASS + t];
        out[g * NCLASS + t] = acc;
    }
}

// ---------------- launch ----------------

extern "C" void kernel_launch(void* const* d_in, const int* in_sizes, int n_in,
                              void* d_out, int out_size, void* d_ws, size_t ws_size,
                              hipStream_t stream) {
    const float* x     = (const float*)d_in[0];
    const int*   eidx  = (const int*)d_in[1];
    const int*   batch = (const int*)d_in[2];
    const float* Wl    = (const float*)d_in[3];
    const float* bl    = (const float*)d_in[4];
    const float* Wr    = (const float*)d_in[5];
    const float* gamma = (const float*)d_in[6];
    const float* beta  = (const float*)d_in[7];
    const float* linW  = (const float*)d_in[8];
    const float* linb  = (const float*)d_in[9];
    float* out = (float*)d_out;

    const int* src = eidx;
    const int* dst = eidx + N_EDGES;

    char* p = (char*)d_ws;
    auto alloc = [&](size_t bytes) { char* r = p; p += (bytes + 255) & ~(size_t)255; return r; };
    unsigned short* Xb   = (unsigned short*)alloc((size_t)N_NODES * HDIM * 2);
    unsigned short* AGGb = (unsigned short*)alloc((size_t)N_NODES * HDIM * 2);
    unsigned short* HbA  = (unsigned short*)alloc((size_t)N_NODES * HDIM * 2);
    unsigned short* HbB  = (unsigned short*)alloc((size_t)N_NODES * HDIM * 2);
    unsigned short* Wtb  = (unsigned short*)alloc((size_t)NLAYER * 2 * HDIM * HDIM * 2);
    int*   row_off = (int*)alloc((N_NODES + 2) * 4);
    int*   col     = (int*)alloc((size_t)N_EDGES * 4);
    int2v* P       = (int2v*)alloc((size_t)N_EDGES * 8);
    int*   bcnt    = (int*)alloc(NBUCK * 4);
    int*   boff    = (int*)alloc((NBUCK + 1) * 4);
    int*   bcur    = (int*)alloc(NBUCK * 4);
    int*   gb      = (int*)alloc((NGRAPH + 2) * 4);
    float* pstat   = (float*)alloc((size_t)NBLK_G * 256 * 4);
    float* red32   = (float*)alloc(32 * 256 * 4);
    float* scsh    = (float*)alloc(2 * HDIM * 4);
    float* ppart   = (float*)alloc((size_t)NGRAPH * POOL_SPLIT * HDIM * 4);
    float* pooled  = (float*)alloc(NGRAPH * HDIM * 4);

    // ---- CSR build v3 ----
    hipMemsetAsync(bcnt, 0, NBUCK * sizeof(int), stream);
    k_hist<<<KC_BLOCKS, 256, 0, stream>>>(dst, bcnt);
    k_bscan<<<1, 64, 0, stream>>>(bcnt, boff, bcur, row_off);
    k_part<<<KC_BLOCKS, 256, 0, stream>>>(src, dst, bcur, P);
    k_bucket<<<NBUCK, 1024, 0, stream>>>(P, boff, row_off, col);

    // ---- one-time converts ----
    k_cvt_x<<<N_NODES * HDIM / 4 / 256, 256, 0, stream>>>(x, Xb);
    k_cvt_w<<<NLAYER * 2 * HDIM * HDIM / 256, 256, 0, stream>>>(Wl, Wr, Wtb);
    k_gbound<<<3, 64, 0, stream>>>(batch, gb);

    // ---- layer 0 ----
    k_aggk<false><<<N_NODES / 16, 256, 0, stream>>>(Xb, scsh, row_off, col, AGGb);
    k_gemm_l0<<<NBLK_G, 512, 0, stream>>>(AGGb, Xb, Wtb, bl, HbA, pstat);
    k_red1<<<32, 256, 0, stream>>>(pstat, red32);
    k_stats_final<<<1, 128, 0, stream>>>(red32, gamma, beta, scsh);

    // ---- layers 1..5 ----
    unsigned short* Hcur = HbA;
    for (int l = 1; l < NLAYER; ++l) {
        unsigned short* Hout = (l & 1) ? HbB : HbA;
        k_aggk<true><<<N_NODES / 16, 256, 0, stream>>>(Hcur, scsh, row_off, col, AGGb);
        k_gemm_fuse<<<NBLK_G, 512, 0, stream>>>(
            AGGb, Hcur, scsh, Wtb + (size_t)l * 2 * HDIM * HDIM, bl + (size_t)l * HDIM,
            Hout, pstat);
        k_red1<<<32, 256, 0, stream>>>(pstat, red32);
        k_stats_final<<<1, 128, 0, stream>>>(red32, gamma + (size_t)l * HDIM,
                                             beta + (size_t)l * HDIM, scsh);
        Hcur = Hout;
    }

    // ---- pool + classifier ----
    k_pool_part<<<dim3(NGRAPH, POOL_SPLIT), 128, 0, stream>>>(Hcur, scsh, gb, ppart);
    k_pool_final<<<NGRAPH, 128, 0, stream>>>(gb, ppart, pooled);
    k_lin<<<NGRAPH, 128, 0, stream>>>(pooled, linW, linb, out);
}

// Round 10
// 593.786 us; speedup vs baseline: 1.7368x; 1.1973x over previous
//
#include <hip/hip_runtime.h>
#include <hip/hip_bf16.h>

#define N_NODES 100000
#define N_EDGES 1600000
#define HDIM    128
#define NLAYER  6
#define NGRAPH  128
#define NCLASS  10
#define BN_EPS  1e-5f

#define POOL_SPLIT 16

#define NBUCK   196          // buckets of 512 nodes (dst >> 9)
#define BSH     9
#define KC_BLOCKS 250
#define KC_CHUNK  6400       // 250 * 6400 = 1.6M edges
#define LCOL_CAP  10240

#define GBM 256
#define NBLK_G ((N_NODES + GBM - 1) / GBM)                     // 391

typedef __attribute__((ext_vector_type(8))) short short8v;
typedef __attribute__((ext_vector_type(4))) float f32x4;
typedef __attribute__((ext_vector_type(2))) float f32x2;
typedef __attribute__((ext_vector_type(4))) int int4v;
typedef __attribute__((ext_vector_type(2))) int int2v;

__device__ __forceinline__ float b2f(unsigned short h) {
    return __uint_as_float(((unsigned int)h) << 16);
}
__device__ __forceinline__ unsigned short f2b(float f) {
    unsigned int u = __float_as_uint(f);
    u += 0x7FFF + ((u >> 16) & 1);          // RNE
    return (unsigned short)(u >> 16);
}
__device__ __forceinline__ void gl_lds16(const void* g, void* l) {
    __builtin_amdgcn_global_load_lds((const __attribute__((address_space(1))) unsigned int*)g,
                                     (__attribute__((address_space(3))) unsigned int*)l,
                                     16, 0, 0);
}
__device__ __forceinline__ short8v bn_pack(short8v v, float4 scA, float4 scB,
                                           float4 shA, float4 shB) {
    short8v o;
    o[0] = (short)f2b(fmaxf(0.f, b2f((unsigned short)v[0]) * scA.x + shA.x));
    o[1] = (short)f2b(fmaxf(0.f, b2f((unsigned short)v[1]) * scA.y + shA.y));
    o[2] = (short)f2b(fmaxf(0.f, b2f((unsigned short)v[2]) * scA.z + shA.z));
    o[3] = (short)f2b(fmaxf(0.f, b2f((unsigned short)v[3]) * scA.w + shA.w));
    o[4] = (short)f2b(fmaxf(0.f, b2f((unsigned short)v[4]) * scB.x + shB.x));
    o[5] = (short)f2b(fmaxf(0.f, b2f((unsigned short)v[5]) * scB.y + shB.y));
    o[6] = (short)f2b(fmaxf(0.f, b2f((unsigned short)v[6]) * scB.z + shB.z));
    o[7] = (short)f2b(fmaxf(0.f, b2f((unsigned short)v[7]) * scB.w + shB.w));
    return o;
}

// ---------------- CSR build v3: bucketed 2-pass radix ----------------

__global__ void __launch_bounds__(256) k_hist(const int* __restrict__ dst,
                                              int* __restrict__ bcnt) {
    __shared__ int h[NBUCK];
    for (int i = threadIdx.x; i < NBUCK; i += 256) h[i] = 0;
    __syncthreads();
    const int4v* d4 = (const int4v*)dst;
    int base = blockIdx.x * (KC_CHUNK / 4);
    for (int i = threadIdx.x; i < KC_CHUNK / 4; i += 256) {
        int4v d = __builtin_nontemporal_load(d4 + base + i);
        atomicAdd(&h[d[0] >> BSH], 1);
        atomicAdd(&h[d[1] >> BSH], 1);
        atomicAdd(&h[d[2] >> BSH], 1);
        atomicAdd(&h[d[3] >> BSH], 1);
    }
    __syncthreads();
    for (int i = threadIdx.x; i < NBUCK; i += 256)
        if (h[i]) atomicAdd(&bcnt[i], h[i]);
}

__global__ void k_bscan(const int* __restrict__ bcnt, int* __restrict__ boff,
                        int* __restrict__ bcur, int* __restrict__ row_off) {
    if (threadIdx.x == 0 && blockIdx.x == 0) {
        int acc = 0;
        for (int i = 0; i < NBUCK; ++i) {
            boff[i] = acc; bcur[i] = acc; acc += bcnt[i];
        }
        boff[NBUCK] = acc;
        row_off[N_NODES] = N_EDGES;
    }
}

__global__ void __launch_bounds__(256) k_part(const int* __restrict__ src,
                                              const int* __restrict__ dst,
                                              int* __restrict__ bcur,
                                              int2v* __restrict__ P) {
    __shared__ int h[NBUCK];
    __shared__ int gbase[NBUCK];
    for (int i = threadIdx.x; i < NBUCK; i += 256) h[i] = 0;
    __syncthreads();
    const int4v* d4 = (const int4v*)dst;
    const int4v* s4 = (const int4v*)src;
    const int base = blockIdx.x * (KC_CHUNK / 4);
    for (int i = threadIdx.x; i < KC_CHUNK / 4; i += 256) {
        int4v d = __builtin_nontemporal_load(d4 + base + i);
        atomicAdd(&h[d[0] >> BSH], 1);
        atomicAdd(&h[d[1] >> BSH], 1);
        atomicAdd(&h[d[2] >> BSH], 1);
        atomicAdd(&h[d[3] >> BSH], 1);
    }
    __syncthreads();
    for (int i = threadIdx.x; i < NBUCK; i += 256) {
        int c = h[i];
        gbase[i] = c ? atomicAdd(&bcur[i], c) : 0;
        h[i] = 0;
    }
    __syncthreads();
    for (int i = threadIdx.x; i < KC_CHUNK / 4; i += 256) {
        int4v d = __builtin_nontemporal_load(d4 + base + i);
        int4v s = __builtin_nontemporal_load(s4 + base + i);
#pragma unroll
        for (int k = 0; k < 4; ++k) {
            int b = d[k] >> BSH;
            int pos = gbase[b] + atomicAdd(&h[b], 1);
            int2v pr; pr[0] = s[k]; pr[1] = d[k];
            P[pos] = pr;
        }
    }
}

__global__ void __launch_bounds__(1024) k_bucket(const int2v* __restrict__ P,
                                                 const int* __restrict__ boff,
                                                 int* __restrict__ row_off,
                                                 int* __restrict__ col) {
    __shared__ int ldeg[512];
    __shared__ int lcur[512];
    __shared__ int lcol[LCOL_CAP];
    const int tid = threadIdx.x;
    const int b = blockIdx.x;
    const int pbeg = boff[b], pend = boff[b + 1];
    const int nE = pend - pbeg;
    const int n0 = b << BSH;
    if (tid < 512) ldeg[tid] = 0;
    __syncthreads();
    for (int i = tid; i < nE; i += 1024) {
        int2v pr = P[pbeg + i];
        atomicAdd(&ldeg[pr[1] - n0], 1);
    }
    __syncthreads();
    int myd = (tid < 512) ? ldeg[tid] : 0;
    for (int off = 1; off < 512; off <<= 1) {
        int t = 0;
        if (tid < 512 && tid >= off) t = ldeg[tid - off];
        __syncthreads();
        if (tid < 512) ldeg[tid] += t;
        __syncthreads();
    }
    if (tid < 512) {
        int excl = ldeg[tid] - myd;
        lcur[tid] = excl;
        int node = n0 + tid;
        if (node < N_NODES) row_off[node] = pbeg + excl;
    }
    __syncthreads();
    for (int i = tid; i < nE; i += 1024) {
        int2v pr = P[pbeg + i];
        int pos = atomicAdd(&lcur[pr[1] - n0], 1);
        if (pos < LCOL_CAP) lcol[pos] = pr[0];
    }
    __syncthreads();
    for (int i = tid; i < nE; i += 1024) col[pbeg + i] = lcol[i];
}

// ---------------- one-time converts ----------------

// x -> Xb (bf16, GEMM root path) and X8 (fp8 e4m3, gather path)
__global__ void __launch_bounds__(256) k_cvt_x(const float* __restrict__ x,
                                               unsigned short* __restrict__ Xb,
                                               unsigned int* __restrict__ X8) {
    int idx = blockIdx.x * 256 + threadIdx.x;          // < N*H/4
    f32x4 v = __builtin_nontemporal_load(((const f32x4*)x) + idx);
    ushort4 o = { f2b(v[0]), f2b(v[1]), f2b(v[2]), f2b(v[3]) };
    ((ushort4*)Xb)[idx] = o;
    unsigned int d = 0;
    d = __builtin_amdgcn_cvt_pk_fp8_f32(v[0], v[1], d, false);
    d = __builtin_amdgcn_cvt_pk_fp8_f32(v[2], v[3], d, true);
    X8[idx] = d;
}

__global__ void __launch_bounds__(256) k_cvt_w(const float* __restrict__ Wl,
                                               const float* __restrict__ Wr,
                                               unsigned short* __restrict__ Wtb) {
    int idx = blockIdx.x * 256 + threadIdx.x;
    int kk = idx & 255;
    int n  = (idx >> 8) & 127;
    int l  = idx >> 15;
    float v = (kk < HDIM) ? Wl[l * HDIM * HDIM + kk * HDIM + n]
                          : Wr[l * HDIM * HDIM + (kk - HDIM) * HDIM + n];
    Wtb[idx] = f2b(v);
}

// X8 = fp8(relu(bn(Hb))) — materialize next-layer gather operand
__global__ void __launch_bounds__(256) k_bnx8(const unsigned short* __restrict__ Hb,
                                              const float* __restrict__ scsh,
                                              int2v* __restrict__ X8) {
    int idx = blockIdx.x * 256 + threadIdx.x;          // ushort8 index, < N*H/8
    int c8 = (idx & 15) * 8;
    short8v v = ((const short8v*)Hb)[idx];
    float f[8];
#pragma unroll
    for (int j = 0; j < 8; ++j)
        f[j] = fmaxf(0.f, b2f((unsigned short)v[j]) * scsh[c8 + j] + scsh[HDIM + c8 + j]);
    unsigned int d0 = 0, d1 = 0;
    d0 = __builtin_amdgcn_cvt_pk_fp8_f32(f[0], f[1], d0, false);
    d0 = __builtin_amdgcn_cvt_pk_fp8_f32(f[2], f[3], d0, true);
    d1 = __builtin_amdgcn_cvt_pk_fp8_f32(f[4], f[5], d1, false);
    d1 = __builtin_amdgcn_cvt_pk_fp8_f32(f[6], f[7], d1, true);
    int2v o; o[0] = (int)d0; o[1] = (int)d1;
    X8[idx] = o;
}

// ---------------- aggregation v4: fp8 gather, pure sum ----------------
// 32 nodes/block, 8 lanes/node, 16 fp8 channels (16B) per lane.
__global__ void __launch_bounds__(256) k_agg8(const unsigned char* __restrict__ X8,
                                              const int* __restrict__ row_off,
                                              const int* __restrict__ col,
                                              unsigned short* __restrict__ AGGb) {
    __shared__ int lcol[4096];
    __shared__ int sro[33];
    const int tid = threadIdx.x;
    const int nb0 = blockIdx.x * 32;
    if (tid <= 32) sro[tid] = row_off[nb0 + tid];
    __syncthreads();
    const int s0 = sro[0];
    const int nE = sro[32] - s0;
    const bool fits = (nE <= 4096);
    if (fits) {
        for (int i = tid; i < nE; i += 256) lcol[i] = col[s0 + i];
    }
    __syncthreads();

    const int g   = tid >> 3;          // node in block
    const int c16 = (tid & 7) * 16;    // channel base
    const int s = sro[g] - s0, e = sro[g + 1] - s0;
    const int* cp = fits ? lcol : (col + s0);

    f32x2 a2[8] = {};
    auto accum = [&](int4v v) {
#pragma unroll
        for (int q = 0; q < 4; ++q) {
            unsigned int w = (unsigned int)v[q];
            a2[2 * q]     += __builtin_amdgcn_cvt_pk_f32_fp8(w, false);
            a2[2 * q + 1] += __builtin_amdgcn_cvt_pk_f32_fp8(w, true);
        }
    };

    int p = s;
    for (; p + 8 <= e; p += 8) {
        int nbx[8];
#pragma unroll
        for (int j = 0; j < 8; ++j) nbx[j] = cp[p + j];
        int4v v[8];
#pragma unroll
        for (int j = 0; j < 8; ++j)
            v[j] = *(const int4v*)(X8 + (size_t)nbx[j] * HDIM + c16);
#pragma unroll
        for (int j = 0; j < 8; ++j) accum(v[j]);
    }
    if (p + 4 <= e) {
        int nbx[4];
#pragma unroll
        for (int j = 0; j < 4; ++j) nbx[j] = cp[p + j];
        int4v v[4];
#pragma unroll
        for (int j = 0; j < 4; ++j)
            v[j] = *(const int4v*)(X8 + (size_t)nbx[j] * HDIM + c16);
#pragma unroll
        for (int j = 0; j < 4; ++j) accum(v[j]);
        p += 4;
    }
    for (; p < e; ++p) {
        int4v v0 = *(const int4v*)(X8 + (size_t)cp[p] * HDIM + c16);
        accum(v0);
    }

    float w = (e > s) ? 1.0f / (float)(e - s) : 0.f;
    short8v o0, o1;
#pragma unroll
    for (int j = 0; j < 8; ++j) o0[j] = (short)f2b(a2[j >> 1][j & 1] * w);
#pragma unroll
    for (int j = 0; j < 8; ++j) o1[j] = (short)f2b(a2[4 + (j >> 1)][j & 1] * w);
    unsigned short* dst = AGGb + (size_t)(nb0 + g) * HDIM + c16;
    *(short8v*)dst = o0;
    *(short8v*)(dst + 8) = o1;
}

// ---------------- GEMMs (256 rows/block, 512 thr, K=256, dbuf, fused BN stats) ----------------

__global__ void __launch_bounds__(512) k_gemm_l0(const unsigned short* __restrict__ AGGb,
                                                 const unsigned short* __restrict__ Xb,
                                                 const unsigned short* __restrict__ Wtb,
                                                 const float* __restrict__ bl,
                                                 unsigned short* __restrict__ Hb,
                                                 float* __restrict__ pstat) {
    __shared__ __align__(16) char smem[49152];
    const int tid  = threadIdx.x;
    const int bm   = blockIdx.x * GBM;
    const int wv   = tid >> 6;
    const int lane = tid & 63;
    const int li   = lane & 15, hi = lane >> 4;

    f32x4 acc[2][8] = {};

    auto stage = [&](int b, int step) {
        const unsigned short* Asrc = (step < 4) ? AGGb : Xb;
        const int kk0 = (step & 3) * 32;
        char* baseA = smem + b * 16384;
        const int sk = tid & 3;
#pragma unroll
        for (int q = 0; q < 2; ++q) {
            int r = q * 128 + (tid >> 2);
            int row = bm + r; if (row >= N_NODES) row = N_NODES - 1;
            gl_lds16((const char*)(Asrc + (size_t)row * HDIM + kk0) + (((sk ^ (r & 3)) & 3) << 4),
                     baseA + (q * 8 + wv) * 1024);
        }
        const int k0 = step * 32;
        {
            int n = tid >> 2;
            gl_lds16((const char*)(Wtb + (size_t)n * 256 + k0) + (((sk ^ (n & 3)) & 3) << 4),
                     smem + 32768 + b * 8192 + wv * 1024);
        }
    };

    stage(0, 0);
    __syncthreads();

    int buf = 0;
    for (int step = 0; step < 8; ++step) {
        if (step < 7) stage(buf ^ 1, step + 1);
        char* bA = smem + buf * 16384;
        char* bW = smem + 32768 + buf * 8192;
        short8v afr[2], bfr[8];
#pragma unroll
        for (int m = 0; m < 2; ++m) {
            int r = wv * 32 + m * 16 + li;
            afr[m] = *(const short8v*)(bA + r * 64 + ((hi ^ (r & 3)) << 4));
        }
#pragma unroll
        for (int nf = 0; nf < 8; ++nf) {
            int n = nf * 16 + li;
            bfr[nf] = *(const short8v*)(bW + n * 64 + ((hi ^ (n & 3)) << 4));
        }
#pragma unroll
        for (int m = 0; m < 2; ++m)
#pragma unroll
            for (int nf = 0; nf < 8; ++nf)
                acc[m][nf] = __builtin_amdgcn_mfma_f32_16x16x32_bf16(afr[m], bfr[nf],
                                                                     acc[m][nf], 0, 0, 0);
        __syncthreads();
        buf ^= 1;
    }

    float* st = (float*)smem;
#pragma unroll
    for (int nf = 0; nf < 8; ++nf) {
        int c = nf * 16 + li;
        float bb = bl[c];
        float ls = 0.f, lq = 0.f;
#pragma unroll
        for (int m = 0; m < 2; ++m) {
            int row0 = bm + wv * 32 + m * 16 + hi * 4;
#pragma unroll
            for (int j = 0; j < 4; ++j) {
                int row = row0 + j;
                if (row < N_NODES) {
                    float v = acc[m][nf][j] + bb;
                    Hb[(size_t)row * HDIM + c] = f2b(v);
                    ls += v; lq += v * v;
                }
            }
        }
        ls += __shfl_xor(ls, 16); ls += __shfl_xor(ls, 32);
        lq += __shfl_xor(lq, 16); lq += __shfl_xor(lq, 32);
        if (hi == 0) {
            st[wv * 128 + c] = ls;
            st[1024 + wv * 128 + c] = lq;
        }
    }
    __syncthreads();
    if (tid < 128) {
        float s = 0.f;
#pragma unroll
        for (int w8 = 0; w8 < 8; ++w8) s += st[w8 * 128 + tid];
        pstat[blockIdx.x * 256 + tid] = s;
    } else if (tid < 256) {
        int c = tid - 128;
        float q = 0.f;
#pragma unroll
        for (int w8 = 0; w8 < 8; ++w8) q += st[1024 + w8 * 128 + c];
        pstat[blockIdx.x * 256 + tid] = q;
    }
}

__global__ void __launch_bounds__(512) k_gemm_fuse(const unsigned short* __restrict__ AGGb,
                                                   const unsigned short* __restrict__ Hprev,
                                                   const float* __restrict__ scsh,
                                                   const unsigned short* __restrict__ Wtb,
                                                   const float* __restrict__ bl,
                                                   unsigned short* __restrict__ Hb,
                                                   float* __restrict__ pstat) {
    __shared__ __align__(16) char smem[49152];
    const int tid  = threadIdx.x;
    const int bm   = blockIdx.x * GBM;
    const int wv   = tid >> 6;
    const int lane = tid & 63;
    const int li   = lane & 15, hi = lane >> 4;
    const int rr   = tid >> 2;            // 0..127
    const int sk   = tid & 3;
    const int swz  = ((sk ^ (rr & 3)) << 4);

    f32x4 acc[2][8] = {};

    auto stageW = [&](int b, int step) {
        const int k0 = step * 32;
        gl_lds16((const char*)(Wtb + (size_t)rr * 256 + k0) + swz,
                 smem + 32768 + b * 8192 + wv * 1024);
    };
    auto stageA = [&](int b, int step) {
        const int kk0 = step * 32;
        char* baseA = smem + b * 16384;
#pragma unroll
        for (int q = 0; q < 2; ++q) {
            int r = q * 128 + rr;
            int row = bm + r; if (row >= N_NODES) row = N_NODES - 1;
            gl_lds16((const char*)(AGGb + (size_t)row * HDIM + kk0) + swz,
                     baseA + (q * 8 + wv) * 1024);
        }
    };

    stageA(0, 0); stageW(0, 0);
    __syncthreads();

    int buf = 0;
    for (int step = 0; step < 8; ++step) {
        char* curA = smem + buf * 16384;
        char* curW = smem + 32768 + buf * 8192;
        char* nxtA = smem + (buf ^ 1) * 16384;
        const int ns = step + 1;
        short8v rv0, rv1;
        int c0 = 0;
        bool regstage = false;
        if (step < 7) {
            stageW(buf ^ 1, ns);
            if (ns < 4) {
                stageA(buf ^ 1, ns);
            } else {
                regstage = true;
                c0 = (ns - 4) * 32 + sk * 8;
                int row0 = bm + rr;       if (row0 >= N_NODES) row0 = N_NODES - 1;
                int row1 = bm + 128 + rr; if (row1 >= N_NODES) row1 = N_NODES - 1;
                rv0 = *(const short8v*)(Hprev + (size_t)row0 * HDIM + c0);
                rv1 = *(const short8v*)(Hprev + (size_t)row1 * HDIM + c0);
            }
        }

        short8v afr[2], bfr[8];
#pragma unroll
        for (int m = 0; m < 2; ++m) {
            int r = wv * 32 + m * 16 + li;
            afr[m] = *(const short8v*)(curA + r * 64 + ((hi ^ (r & 3)) << 4));
        }
#pragma unroll
        for (int nf = 0; nf < 8; ++nf) {
            int n = nf * 16 + li;
            bfr[nf] = *(const short8v*)(curW + n * 64 + ((hi ^ (n & 3)) << 4));
        }
#pragma unroll
        for (int m = 0; m < 2; ++m)
#pragma unroll
            for (int nf = 0; nf < 8; ++nf)
                acc[m][nf] = __builtin_amdgcn_mfma_f32_16x16x32_bf16(afr[m], bfr[nf],
                                                                     acc[m][nf], 0, 0, 0);

        if (regstage) {
            float4 scA = *(const float4*)&scsh[c0];
            float4 scB = *(const float4*)&scsh[c0 + 4];
            float4 shA = *(const float4*)&scsh[HDIM + c0];
            float4 shB = *(const float4*)&scsh[HDIM + c0 + 4];
            *(short8v*)(nxtA + rr * 64 + swz)         = bn_pack(rv0, scA, scB, shA, shB);
            *(short8v*)(nxtA + (128 + rr) * 64 + swz) = bn_pack(rv1, scA, scB, shA, shB);
        }
        __syncthreads();
        buf ^= 1;
    }

    float* st = (float*)smem;
#pragma unroll
    for (int nf = 0; nf < 8; ++nf) {
        int c = nf * 16 + li;
        float bb = bl[c];
        float ls = 0.f, lq = 0.f;
#pragma unroll
        for (int m = 0; m < 2; ++m) {
            int row0 = bm + wv * 32 + m * 16 + hi * 4;
#pragma unroll
            for (int j = 0; j < 4; ++j) {
                int row = row0 + j;
                if (row < N_NODES) {
                    float v = acc[m][nf][j] + bb;
                    Hb[(size_t)row * HDIM + c] = f2b(v);
                    ls += v; lq += v * v;
                }
            }
        }
        ls += __shfl_xor(ls, 16); ls += __shfl_xor(ls, 32);
        lq += __shfl_xor(lq, 16); lq += __shfl_xor(lq, 32);
        if (hi == 0) {
            st[wv * 128 + c] = ls;
            st[1024 + wv * 128 + c] = lq;
        }
    }
    __syncthreads();
    if (tid < 128) {
        float s = 0.f;
#pragma unroll
        for (int w8 = 0; w8 < 8; ++w8) s += st[w8 * 128 + tid];
        pstat[blockIdx.x * 256 + tid] = s;
    } else if (tid < 256) {
        int c = tid - 128;
        float q = 0.f;
#pragma unroll
        for (int w8 = 0; w8 < 8; ++w8) q += st[1024 + w8 * 128 + c];
        pstat[blockIdx.x * 256 + tid] = q;
    }
}

__global__ void __launch_bounds__(256) k_red1(const float* __restrict__ pstat,
                                              float* __restrict__ red32) {
    int c = threadIdx.x, b = blockIdx.x;
    float s = 0.f;
    for (int r = b; r < NBLK_G; r += 32) s += pstat[r * 256 + c];
    red32[b * 256 + c] = s;
}

__global__ void __launch_bounds__(128) k_stats_final(const float* __restrict__ red32,
                                                     const float* __restrict__ gamma,
                                                     const float* __restrict__ beta,
                                                     float* __restrict__ scsh) {
    int c = threadIdx.x;
    float s = 0.f, q = 0.f;
    for (int r = 0; r < 32; ++r) { s += red32[r * 256 + c]; q += red32[r * 256 + 128 + c]; }
    float mu = s / (float)N_NODES;
    float var = q / (float)N_NODES - mu * mu;
    float rs = rsqrtf(var + BN_EPS);
    float sc = gamma[c] * rs;
    scsh[c] = sc;
    scsh[HDIM + c] = beta[c] - mu * sc;
}

// ---------------- pooling + classifier ----------------

__global__ void k_gbound(const int* __restrict__ batch, int* __restrict__ gb) {
    int t = blockIdx.x * 64 + threadIdx.x;
    if (t > NGRAPH) return;
    int lo = 0, hi = N_NODES;
    while (lo < hi) { int mid = (lo + hi) >> 1; if (batch[mid] < t) lo = mid + 1; else hi = mid; }
    gb[t] = lo;
}

__global__ void __launch_bounds__(128) k_pool_part(const unsigned short* __restrict__ Hb,
                                                   const float* __restrict__ scsh,
                                                   const int* __restrict__ gb,
                                                   float* __restrict__ ppart) {
    int g = blockIdx.x, sp = blockIdx.y;
    int c = threadIdx.x;
    float sc = scsh[c], sh = scsh[HDIM + c];
    int s = gb[g], e = gb[g + 1];
    float acc = 0.f;
    for (int i = s + sp; i < e; i += POOL_SPLIT)
        acc += fmaxf(0.f, b2f(Hb[(size_t)i * HDIM + c]) * sc + sh);
    ppart[(g * POOL_SPLIT + sp) * HDIM + c] = acc;
}

__global__ void __launch_bounds__(128) k_pool_final(const int* __restrict__ gb,
                                                    const float* __restrict__ ppart,
                                                    float* __restrict__ pooled) {
    int g = blockIdx.x, c = threadIdx.x;
    float s = 0.f;
    for (int sp = 0; sp < POOL_SPLIT; ++sp) s += ppart[(g * POOL_SPLIT + sp) * HDIM + c];
    int cnt = gb[g + 1] - gb[g]; if (cnt < 1) cnt = 1;
    pooled[g * HDIM + c] = s / (float)cnt;
}

__global__ void __launch_bounds__(128) k_lin(const float* __restrict__ pooled,
                                             const float* __restrict__ W,
                                             const float* __restrict__ bvec,
                                             float* __restrict__ out) {
    __shared__ float p[HDIM];
    int g = blockIdx.x, t = threadIdx.x;
    p[t] = pooled[g * HDIM + t];
    __syncthreads();
    if (t < NCLASS) {
        float acc = bvec[t];
        for (int k = 0; k < HDIM; ++k) acc += p[k] * W[k * NCLASS + t];
        out[g * NCLASS + t] = acc;
    }
}

// ---------------- launch ----------------

extern "C" void kernel_launch(void* const* d_in, const int* in_sizes, int n_in,
                              void* d_out, int out_size, void* d_ws, size_t ws_size,
                              hipStream_t stream) {
    const float* x     = (const float*)d_in[0];
    const int*   eidx  = (const int*)d_in[1];
    const int*   batch = (const int*)d_in[2];
    const float* Wl    = (const float*)d_in[3];
    const float* bl    = (const float*)d_in[4];
    const float* Wr    = (const float*)d_in[5];
    const float* gamma = (const float*)d_in[6];
    const float* beta  = (const float*)d_in[7];
    const float* linW  = (const float*)d_in[8];
    const float* linb  = (const float*)d_in[9];
    float* out = (float*)d_out;

    const int* src = eidx;
    const int* dst = eidx + N_EDGES;

    char* p = (char*)d_ws;
    auto alloc = [&](size_t bytes) { char* r = p; p += (bytes + 255) & ~(size_t)255; return r; };
    unsigned short* Xb   = (unsigned short*)alloc((size_t)N_NODES * HDIM * 2);
    unsigned char*  X8   = (unsigned char*)alloc((size_t)N_NODES * HDIM);
    unsigned short* AGGb = (unsigned short*)alloc((size_t)N_NODES * HDIM * 2);
    unsigned short* HbA  = (unsigned short*)alloc((size_t)N_NODES * HDIM * 2);
    unsigned short* HbB  = (unsigned short*)alloc((size_t)N_NODES * HDIM * 2);
    unsigned short* Wtb  = (unsigned short*)alloc((size_t)NLAYER * 2 * HDIM * HDIM * 2);
    int*   row_off = (int*)alloc((N_NODES + 2) * 4);
    int*   col     = (int*)alloc((size_t)N_EDGES * 4);
    int2v* P       = (int2v*)alloc((size_t)N_EDGES * 8);
    int*   bcnt    = (int*)alloc(NBUCK * 4);
    int*   boff    = (int*)alloc((NBUCK + 1) * 4);
    int*   bcur    = (int*)alloc(NBUCK * 4);
    int*   gb      = (int*)alloc((NGRAPH + 2) * 4);
    float* pstat   = (float*)alloc((size_t)NBLK_G * 256 * 4);
    float* red32   = (float*)alloc(32 * 256 * 4);
    float* scsh    = (float*)alloc(2 * HDIM * 4);
    float* ppart   = (float*)alloc((size_t)NGRAPH * POOL_SPLIT * HDIM * 4);
    float* pooled  = (float*)alloc(NGRAPH * HDIM * 4);

    // ---- CSR build v3 ----
    hipMemsetAsync(bcnt, 0, NBUCK * sizeof(int), stream);
    k_hist<<<KC_BLOCKS, 256, 0, stream>>>(dst, bcnt);
    k_bscan<<<1, 64, 0, stream>>>(bcnt, boff, bcur, row_off);
    k_part<<<KC_BLOCKS, 256, 0, stream>>>(src, dst, bcur, P);
    k_bucket<<<NBUCK, 1024, 0, stream>>>(P, boff, row_off, col);

    // ---- one-time converts ----
    k_cvt_x<<<N_NODES * HDIM / 4 / 256, 256, 0, stream>>>(x, Xb, (unsigned int*)X8);
    k_cvt_w<<<NLAYER * 2 * HDIM * HDIM / 256, 256, 0, stream>>>(Wl, Wr, Wtb);
    k_gbound<<<3, 64, 0, stream>>>(batch, gb);

    // ---- layer 0 ----
    k_agg8<<<N_NODES / 32, 256, 0, stream>>>(X8, row_off, col, AGGb);
    k_gemm_l0<<<NBLK_G, 512, 0, stream>>>(AGGb, Xb, Wtb, bl, HbA, pstat);
    k_red1<<<32, 256, 0, stream>>>(pstat, red32);
    k_stats_final<<<1, 128, 0, stream>>>(red32, gamma, beta, scsh);

    // ---- layers 1..5 ----
    unsigned short* Hcur = HbA;
    for (int l = 1; l < NLAYER; ++l) {
        unsigned short* Hout = (l & 1) ? HbB : HbA;
        k_bnx8<<<N_NODES * HDIM / 8 / 256, 256, 0, stream>>>(Hcur, scsh, (int2v*)X8);
        k_agg8<<<N_NODES / 32, 256, 0, stream>>>(X8, row_off, col, AGGb);
        k_gemm_fuse<<<NBLK_G, 512, 0, stream>>>(
            AGGb, Hcur, scsh, Wtb + (size_t)l * 2 * HDIM * HDIM, bl + (size_t)l * HDIM,
            Hout, pstat);
        k_red1<<<32, 256, 0, stream>>>(pstat, red32);
        k_stats_final<<<1, 128, 0, stream>>>(red32, gamma + (size_t)l * HDIM,
                                             beta + (size_t)l * HDIM, scsh);
        Hcur = Hout;
    }

    // ---- pool + classifier ----
    k_pool_part<<<dim3(NGRAPH, POOL_SPLIT), 128, 0, stream>>>(Hcur, scsh, gb, ppart);
    k_pool_final<<<NGRAPH, 128, 0, stream>>>(gb, ppart, pooled);
    k_lin<<<NGRAPH, 128, 0, stream>>>(pooled, linW, linb, out);
}

// Round 11
// 562.520 us; speedup vs baseline: 1.8334x; 1.0556x over previous
//
#include <hip/hip_runtime.h>
#include <hip/hip_bf16.h>

#define N_NODES 100000
#define N_EDGES 1600000
#define HDIM    128
#define NLAYER  6
#define NGRAPH  128
#define NCLASS  10
#define BN_EPS  1e-5f

#define POOL_SPLIT 16

#define NBUCK   196          // buckets of 512 nodes (dst >> 9)
#define BSH     9
#define KC_BLOCKS 250
#define KC_CHUNK  6400       // 250 * 6400 = 1.6M edges
#define LCOL_CAP  10240

#define GBM 128
#define NBLK_G ((N_NODES + GBM - 1) / GBM)                     // 782

typedef __attribute__((ext_vector_type(8))) short short8v;
typedef __attribute__((ext_vector_type(4))) float f32x4;
typedef __attribute__((ext_vector_type(2))) float f32x2;
typedef __attribute__((ext_vector_type(4))) int int4v;
typedef __attribute__((ext_vector_type(2))) int int2v;

__device__ __forceinline__ float b2f(unsigned short h) {
    return __uint_as_float(((unsigned int)h) << 16);
}
__device__ __forceinline__ unsigned short f2b(float f) {
    unsigned int u = __float_as_uint(f);
    u += 0x7FFF + ((u >> 16) & 1);          // RNE
    return (unsigned short)(u >> 16);
}
__device__ __forceinline__ void gl_lds16(const void* g, void* l) {
    __builtin_amdgcn_global_load_lds((const __attribute__((address_space(1))) unsigned int*)g,
                                     (__attribute__((address_space(3))) unsigned int*)l,
                                     16, 0, 0);
}
__device__ __forceinline__ short8v bn_pack(short8v v, float4 scA, float4 scB,
                                           float4 shA, float4 shB) {
    short8v o;
    o[0] = (short)f2b(fmaxf(0.f, b2f((unsigned short)v[0]) * scA.x + shA.x));
    o[1] = (short)f2b(fmaxf(0.f, b2f((unsigned short)v[1]) * scA.y + shA.y));
    o[2] = (short)f2b(fmaxf(0.f, b2f((unsigned short)v[2]) * scA.z + shA.z));
    o[3] = (short)f2b(fmaxf(0.f, b2f((unsigned short)v[3]) * scA.w + shA.w));
    o[4] = (short)f2b(fmaxf(0.f, b2f((unsigned short)v[4]) * scB.x + shB.x));
    o[5] = (short)f2b(fmaxf(0.f, b2f((unsigned short)v[5]) * scB.y + shB.y));
    o[6] = (short)f2b(fmaxf(0.f, b2f((unsigned short)v[6]) * scB.z + shB.z));
    o[7] = (short)f2b(fmaxf(0.f, b2f((unsigned short)v[7]) * scB.w + shB.w));
    return o;
}

// ---------------- CSR build v3: bucketed 2-pass radix ----------------

__global__ void __launch_bounds__(256) k_hist(const int* __restrict__ dst,
                                              int* __restrict__ bcnt) {
    __shared__ int h[NBUCK];
    for (int i = threadIdx.x; i < NBUCK; i += 256) h[i] = 0;
    __syncthreads();
    const int4v* d4 = (const int4v*)dst;
    int base = blockIdx.x * (KC_CHUNK / 4);
    for (int i = threadIdx.x; i < KC_CHUNK / 4; i += 256) {
        int4v d = __builtin_nontemporal_load(d4 + base + i);
        atomicAdd(&h[d[0] >> BSH], 1);
        atomicAdd(&h[d[1] >> BSH], 1);
        atomicAdd(&h[d[2] >> BSH], 1);
        atomicAdd(&h[d[3] >> BSH], 1);
    }
    __syncthreads();
    for (int i = threadIdx.x; i < NBUCK; i += 256)
        if (h[i]) atomicAdd(&bcnt[i], h[i]);
}

__global__ void k_bscan(const int* __restrict__ bcnt, int* __restrict__ boff,
                        int* __restrict__ bcur, int* __restrict__ row_off) {
    if (threadIdx.x == 0 && blockIdx.x == 0) {
        int acc = 0;
        for (int i = 0; i < NBUCK; ++i) {
            boff[i] = acc; bcur[i] = acc; acc += bcnt[i];
        }
        boff[NBUCK] = acc;
        row_off[N_NODES] = N_EDGES;
    }
}

__global__ void __launch_bounds__(256) k_part(const int* __restrict__ src,
                                              const int* __restrict__ dst,
                                              int* __restrict__ bcur,
                                              int2v* __restrict__ P) {
    __shared__ int h[NBUCK];
    __shared__ int gbase[NBUCK];
    for (int i = threadIdx.x; i < NBUCK; i += 256) h[i] = 0;
    __syncthreads();
    const int4v* d4 = (const int4v*)dst;
    const int4v* s4 = (const int4v*)src;
    const int base = blockIdx.x * (KC_CHUNK / 4);
    for (int i = threadIdx.x; i < KC_CHUNK / 4; i += 256) {
        int4v d = __builtin_nontemporal_load(d4 + base + i);
        atomicAdd(&h[d[0] >> BSH], 1);
        atomicAdd(&h[d[1] >> BSH], 1);
        atomicAdd(&h[d[2] >> BSH], 1);
        atomicAdd(&h[d[3] >> BSH], 1);
    }
    __syncthreads();
    for (int i = threadIdx.x; i < NBUCK; i += 256) {
        int c = h[i];
        gbase[i] = c ? atomicAdd(&bcur[i], c) : 0;
        h[i] = 0;
    }
    __syncthreads();
    for (int i = threadIdx.x; i < KC_CHUNK / 4; i += 256) {
        int4v d = __builtin_nontemporal_load(d4 + base + i);
        int4v s = __builtin_nontemporal_load(s4 + base + i);
#pragma unroll
        for (int k = 0; k < 4; ++k) {
            int b = d[k] >> BSH;
            int pos = gbase[b] + atomicAdd(&h[b], 1);
            int2v pr; pr[0] = s[k]; pr[1] = d[k];
            P[pos] = pr;
        }
    }
}

__global__ void __launch_bounds__(1024) k_bucket(const int2v* __restrict__ P,
                                                 const int* __restrict__ boff,
                                                 int* __restrict__ row_off,
                                                 int* __restrict__ col) {
    __shared__ int ldeg[512];
    __shared__ int lcur[512];
    __shared__ int lcol[LCOL_CAP];
    const int tid = threadIdx.x;
    const int b = blockIdx.x;
    const int pbeg = boff[b], pend = boff[b + 1];
    const int nE = pend - pbeg;
    const int n0 = b << BSH;
    if (tid < 512) ldeg[tid] = 0;
    __syncthreads();
    for (int i = tid; i < nE; i += 1024) {
        int2v pr = P[pbeg + i];
        atomicAdd(&ldeg[pr[1] - n0], 1);
    }
    __syncthreads();
    int myd = (tid < 512) ? ldeg[tid] : 0;
    for (int off = 1; off < 512; off <<= 1) {
        int t = 0;
        if (tid < 512 && tid >= off) t = ldeg[tid - off];
        __syncthreads();
        if (tid < 512) ldeg[tid] += t;
        __syncthreads();
    }
    if (tid < 512) {
        int excl = ldeg[tid] - myd;
        lcur[tid] = excl;
        int node = n0 + tid;
        if (node < N_NODES) row_off[node] = pbeg + excl;
    }
    __syncthreads();
    for (int i = tid; i < nE; i += 1024) {
        int2v pr = P[pbeg + i];
        int pos = atomicAdd(&lcur[pr[1] - n0], 1);
        if (pos < LCOL_CAP) lcol[pos] = pr[0];
    }
    __syncthreads();
    for (int i = tid; i < nE; i += 1024) col[pbeg + i] = lcol[i];
}

// ---------------- one-time converts ----------------

__global__ void __launch_bounds__(256) k_cvt_x(const float* __restrict__ x,
                                               unsigned short* __restrict__ Xb,
                                               unsigned int* __restrict__ X8) {
    int idx = blockIdx.x * 256 + threadIdx.x;          // < N*H/4
    f32x4 v = __builtin_nontemporal_load(((const f32x4*)x) + idx);
    ushort4 o = { f2b(v[0]), f2b(v[1]), f2b(v[2]), f2b(v[3]) };
    ((ushort4*)Xb)[idx] = o;
    unsigned int d = 0;
    d = __builtin_amdgcn_cvt_pk_fp8_f32(v[0], v[1], d, false);
    d = __builtin_amdgcn_cvt_pk_fp8_f32(v[2], v[3], d, true);
    X8[idx] = d;
}

__global__ void __launch_bounds__(256) k_cvt_w(const float* __restrict__ Wl,
                                               const float* __restrict__ Wr,
                                               unsigned short* __restrict__ Wtb) {
    int idx = blockIdx.x * 256 + threadIdx.x;
    int kk = idx & 255;
    int n  = (idx >> 8) & 127;
    int l  = idx >> 15;
    float v = (kk < HDIM) ? Wl[l * HDIM * HDIM + kk * HDIM + n]
                          : Wr[l * HDIM * HDIM + (kk - HDIM) * HDIM + n];
    Wtb[idx] = f2b(v);
}

// X8 = fp8(relu(bn(Hb)))
__global__ void __launch_bounds__(256) k_bnx8(const unsigned short* __restrict__ Hb,
                                              const float* __restrict__ scsh,
                                              int2v* __restrict__ X8) {
    int idx = blockIdx.x * 256 + threadIdx.x;          // ushort8 index
    int c8 = (idx & 15) * 8;
    short8v v = ((const short8v*)Hb)[idx];
    float f[8];
#pragma unroll
    for (int j = 0; j < 8; ++j)
        f[j] = fmaxf(0.f, b2f((unsigned short)v[j]) * scsh[c8 + j] + scsh[HDIM + c8 + j]);
    unsigned int d0 = 0, d1 = 0;
    d0 = __builtin_amdgcn_cvt_pk_fp8_f32(f[0], f[1], d0, false);
    d0 = __builtin_amdgcn_cvt_pk_fp8_f32(f[2], f[3], d0, true);
    d1 = __builtin_amdgcn_cvt_pk_fp8_f32(f[4], f[5], d1, false);
    d1 = __builtin_amdgcn_cvt_pk_fp8_f32(f[6], f[7], d1, true);
    int2v o; o[0] = (int)d0; o[1] = (int)d1;
    X8[idx] = o;
}

// ---------------- aggregation v4: fp8 gather, pure sum ----------------

__global__ void __launch_bounds__(256) k_agg8(const unsigned char* __restrict__ X8,
                                              const int* __restrict__ row_off,
                                              const int* __restrict__ col,
                                              unsigned short* __restrict__ AGGb) {
    __shared__ int lcol[4096];
    __shared__ int sro[33];
    const int tid = threadIdx.x;
    const int nb0 = blockIdx.x * 32;
    if (tid <= 32) sro[tid] = row_off[nb0 + tid];
    __syncthreads();
    const int s0 = sro[0];
    const int nE = sro[32] - s0;
    const bool fits = (nE <= 4096);
    if (fits) {
        for (int i = tid; i < nE; i += 256) lcol[i] = col[s0 + i];
    }
    __syncthreads();

    const int g   = tid >> 3;
    const int c16 = (tid & 7) * 16;
    const int s = sro[g] - s0, e = sro[g + 1] - s0;
    const int* cp = fits ? lcol : (col + s0);

    f32x2 a2[8] = {};
    auto accum = [&](int4v v) {
#pragma unroll
        for (int q = 0; q < 4; ++q) {
            unsigned int w = (unsigned int)v[q];
            a2[2 * q]     += __builtin_amdgcn_cvt_pk_f32_fp8(w, false);
            a2[2 * q + 1] += __builtin_amdgcn_cvt_pk_f32_fp8(w, true);
        }
    };

    int p = s;
    for (; p + 8 <= e; p += 8) {
        int nbx[8];
#pragma unroll
        for (int j = 0; j < 8; ++j) nbx[j] = cp[p + j];
        int4v v[8];
#pragma unroll
        for (int j = 0; j < 8; ++j)
            v[j] = *(const int4v*)(X8 + (size_t)nbx[j] * HDIM + c16);
#pragma unroll
        for (int j = 0; j < 8; ++j) accum(v[j]);
    }
    if (p + 4 <= e) {
        int nbx[4];
#pragma unroll
        for (int j = 0; j < 4; ++j) nbx[j] = cp[p + j];
        int4v v[4];
#pragma unroll
        for (int j = 0; j < 4; ++j)
            v[j] = *(const int4v*)(X8 + (size_t)nbx[j] * HDIM + c16);
#pragma unroll
        for (int j = 0; j < 4; ++j) accum(v[j]);
        p += 4;
    }
    for (; p < e; ++p) {
        int4v v0 = *(const int4v*)(X8 + (size_t)cp[p] * HDIM + c16);
        accum(v0);
    }

    float w = (e > s) ? 1.0f / (float)(e - s) : 0.f;
    short8v o0, o1;
#pragma unroll
    for (int j = 0; j < 8; ++j) o0[j] = (short)f2b(a2[j >> 1][j & 1] * w);
#pragma unroll
    for (int j = 0; j < 8; ++j) o1[j] = (short)f2b(a2[4 + (j >> 1)][j & 1] * w);
    unsigned short* dst = AGGb + (size_t)(nb0 + g) * HDIM + c16;
    *(short8v*)dst = o0;
    *(short8v*)(dst + 8) = o1;
}

// ---------------- GEMMs (128 rows/block, 512 thr = 8 waves 2m x 4n, dbuf) ----------------
// LDS 32KB: A dbuf 2x8KB @0, W dbuf 2x8KB @16384. Invariant: LDS[r][j^(r&3)] = G[r][j].

__global__ void __launch_bounds__(512) k_gemm_l0(const unsigned short* __restrict__ AGGb,
                                                 const unsigned short* __restrict__ Xb,
                                                 const unsigned short* __restrict__ Wtb,
                                                 const float* __restrict__ bl,
                                                 unsigned short* __restrict__ Hb,
                                                 float* __restrict__ pstat) {
    __shared__ __align__(16) char smem[32768];
    const int tid  = threadIdx.x;
    const int bm   = blockIdx.x * GBM;
    const int wv   = tid >> 6;
    const int lane = tid & 63;
    const int li   = lane & 15, hi = lane >> 4;
    const int wm   = wv & 1, wn = wv >> 1;     // 2 x 4 wave grid

    f32x4 acc[4][2] = {};
    const int rr = tid >> 2, sk = tid & 3;
    const int swz = ((sk ^ (rr & 3)) << 4);

    auto stage = [&](int b, int step) {
        const unsigned short* Asrc = (step < 4) ? AGGb : Xb;
        const int kk0 = (step & 3) * 32;
        {
            int row = bm + rr; if (row >= N_NODES) row = N_NODES - 1;
            gl_lds16((const char*)(Asrc + (size_t)row * HDIM + kk0) + swz,
                     smem + b * 8192 + wv * 1024);
        }
        const int k0 = step * 32;
        gl_lds16((const char*)(Wtb + (size_t)rr * 256 + k0) + swz,
                 smem + 16384 + b * 8192 + wv * 1024);
    };

    stage(0, 0);
    __syncthreads();

    int buf = 0;
    for (int step = 0; step < 8; ++step) {
        if (step < 7) stage(buf ^ 1, step + 1);
        char* bA = smem + buf * 8192;
        char* bW = smem + 16384 + buf * 8192;
        short8v afr[4], bfr[2];
#pragma unroll
        for (int m = 0; m < 4; ++m) {
            int r = wm * 64 + m * 16 + li;
            afr[m] = *(const short8v*)(bA + r * 64 + ((hi ^ (r & 3)) << 4));
        }
#pragma unroll
        for (int nf = 0; nf < 2; ++nf) {
            int n = wn * 32 + nf * 16 + li;
            bfr[nf] = *(const short8v*)(bW + n * 64 + ((hi ^ (n & 3)) << 4));
        }
#pragma unroll
        for (int m = 0; m < 4; ++m)
#pragma unroll
            for (int nf = 0; nf < 2; ++nf)
                acc[m][nf] = __builtin_amdgcn_mfma_f32_16x16x32_bf16(afr[m], bfr[nf],
                                                                     acc[m][nf], 0, 0, 0);
        __syncthreads();
        buf ^= 1;
    }

    float* st = (float*)smem;   // [8 wv][128 c] sums @0, sqs @1024
#pragma unroll
    for (int nf = 0; nf < 2; ++nf) {
        int c = wn * 32 + nf * 16 + li;
        float bb = bl[c];
        float ls = 0.f, lq = 0.f;
#pragma unroll
        for (int m = 0; m < 4; ++m) {
            int row0 = bm + wm * 64 + m * 16 + hi * 4;
#pragma unroll
            for (int j = 0; j < 4; ++j) {
                int row = row0 + j;
                if (row < N_NODES) {
                    float v = acc[m][nf][j] + bb;
                    Hb[(size_t)row * HDIM + c] = f2b(v);
                    ls += v; lq += v * v;
                }
            }
        }
        ls += __shfl_xor(ls, 16); ls += __shfl_xor(ls, 32);
        lq += __shfl_xor(lq, 16); lq += __shfl_xor(lq, 32);
        if (hi == 0) {
            st[wv * 128 + c] = ls;
            st[1024 + wv * 128 + c] = lq;
        }
    }
    __syncthreads();
    if (tid < 128) {
        int w0 = (tid >> 5) * 2;                      // waves covering this column
        float s = st[w0 * 128 + tid] + st[(w0 + 1) * 128 + tid];
        pstat[blockIdx.x * 256 + tid] = s;
    } else if (tid < 256) {
        int c = tid - 128;
        int w0 = (c >> 5) * 2;
        float q = st[1024 + w0 * 128 + c] + st[1024 + (w0 + 1) * 128 + c];
        pstat[blockIdx.x * 256 + tid] = q;
    }
}

__global__ void __launch_bounds__(512) k_gemm_fuse(const unsigned short* __restrict__ AGGb,
                                                   const unsigned short* __restrict__ Hprev,
                                                   const float* __restrict__ scsh,
                                                   const unsigned short* __restrict__ Wtb,
                                                   const float* __restrict__ bl,
                                                   unsigned short* __restrict__ Hb,
                                                   float* __restrict__ pstat) {
    __shared__ __align__(16) char smem[32768];
    const int tid  = threadIdx.x;
    const int bm   = blockIdx.x * GBM;
    const int wv   = tid >> 6;
    const int lane = tid & 63;
    const int li   = lane & 15, hi = lane >> 4;
    const int wm   = wv & 1, wn = wv >> 1;

    f32x4 acc[4][2] = {};
    const int rr = tid >> 2, sk = tid & 3;
    const int swz = ((sk ^ (rr & 3)) << 4);

    auto stageW = [&](int b, int step) {
        const int k0 = step * 32;
        gl_lds16((const char*)(Wtb + (size_t)rr * 256 + k0) + swz,
                 smem + 16384 + b * 8192 + wv * 1024);
    };
    auto stageA = [&](int b, int step) {     // AGGb, steps 0..3
        const int kk0 = step * 32;
        int row = bm + rr; if (row >= N_NODES) row = N_NODES - 1;
        gl_lds16((const char*)(AGGb + (size_t)row * HDIM + kk0) + swz,
                 smem + b * 8192 + wv * 1024);
    };

    stageA(0, 0); stageW(0, 0);
    __syncthreads();

    int buf = 0;
    for (int step = 0; step < 8; ++step) {
        char* curA = smem + buf * 8192;
        char* curW = smem + 16384 + buf * 8192;
        char* nxtA = smem + (buf ^ 1) * 8192;
        const int ns = step + 1;
        short8v rv;
        int c0 = 0;
        bool regstage = false;
        if (step < 7) {
            stageW(buf ^ 1, ns);
            if (ns < 4) {
                stageA(buf ^ 1, ns);
            } else {
                regstage = true;
                c0 = (ns - 4) * 32 + sk * 8;
                int row = bm + rr; if (row >= N_NODES) row = N_NODES - 1;
                rv = *(const short8v*)(Hprev + (size_t)row * HDIM + c0);
            }
        }

        short8v afr[4], bfr[2];
#pragma unroll
        for (int m = 0; m < 4; ++m) {
            int r = wm * 64 + m * 16 + li;
            afr[m] = *(const short8v*)(curA + r * 64 + ((hi ^ (r & 3)) << 4));
        }
#pragma unroll
        for (int nf = 0; nf < 2; ++nf) {
            int n = wn * 32 + nf * 16 + li;
            bfr[nf] = *(const short8v*)(curW + n * 64 + ((hi ^ (n & 3)) << 4));
        }
#pragma unroll
        for (int m = 0; m < 4; ++m)
#pragma unroll
            for (int nf = 0; nf < 2; ++nf)
                acc[m][nf] = __builtin_amdgcn_mfma_f32_16x16x32_bf16(afr[m], bfr[nf],
                                                                     acc[m][nf], 0, 0, 0);

        if (regstage) {
            float4 scA = *(const float4*)&scsh[c0];
            float4 scB = *(const float4*)&scsh[c0 + 4];
            float4 shA = *(const float4*)&scsh[HDIM + c0];
            float4 shB = *(const float4*)&scsh[HDIM + c0 + 4];
            *(short8v*)(nxtA + rr * 64 + swz) = bn_pack(rv, scA, scB, shA, shB);
        }
        __syncthreads();
        buf ^= 1;
    }

    float* st = (float*)smem;
#pragma unroll
    for (int nf = 0; nf < 2; ++nf) {
        int c = wn * 32 + nf * 16 + li;
        float bb = bl[c];
        float ls = 0.f, lq = 0.f;
#pragma unroll
        for (int m = 0; m < 4; ++m) {
            int row0 = bm + wm * 64 + m * 16 + hi * 4;
#pragma unroll
            for (int j = 0; j < 4; ++j) {
                int row = row0 + j;
                if (row < N_NODES) {
                    float v = acc[m][nf][j] + bb;
                    Hb[(size_t)row * HDIM + c] = f2b(v);
                    ls += v; lq += v * v;
                }
            }
        }
        ls += __shfl_xor(ls, 16); ls += __shfl_xor(ls, 32);
        lq += __shfl_xor(lq, 16); lq += __shfl_xor(lq, 32);
        if (hi == 0) {
            st[wv * 128 + c] = ls;
            st[1024 + wv * 128 + c] = lq;
        }
    }
    __syncthreads();
    if (tid < 128) {
        int w0 = (tid >> 5) * 2;
        float s = st[w0 * 128 + tid] + st[(w0 + 1) * 128 + tid];
        pstat[blockIdx.x * 256 + tid] = s;
    } else if (tid < 256) {
        int c = tid - 128;
        int w0 = (c >> 5) * 2;
        float q = st[1024 + w0 * 128 + c] + st[1024 + (w0 + 1) * 128 + c];
        pstat[blockIdx.x * 256 + tid] = q;
    }
}

__global__ void __launch_bounds__(256) k_red1(const float* __restrict__ pstat,
                                              float* __restrict__ red32) {
    int c = threadIdx.x, b = blockIdx.x;
    float s = 0.f;
    for (int r = b; r < NBLK_G; r += 32) s += pstat[r * 256 + c];
    red32[b * 256 + c] = s;
}

__global__ void __launch_bounds__(128) k_stats_final(const float* __restrict__ red32,
                                                     const float* __restrict__ gamma,
                                                     const float* __restrict__ beta,
                                                     float* __restrict__ scsh) {
    int c = threadIdx.x;
    float s = 0.f, q = 0.f;
    for (int r = 0; r < 32; ++r) { s += red32[r * 256 + c]; q += red32[r * 256 + 128 + c]; }
    float mu = s / (float)N_NODES;
    float var = q / (float)N_NODES - mu * mu;
    float rs = rsqrtf(var + BN_EPS);
    float sc = gamma[c] * rs;
    scsh[c] = sc;
    scsh[HDIM + c] = beta[c] - mu * sc;
}

// ---------------- pooling + classifier ----------------

__global__ void k_gbound(const int* __restrict__ batch, int* __restrict__ gb) {
    int t = blockIdx.x * 64 + threadIdx.x;
    if (t > NGRAPH) return;
    int lo = 0, hi = N_NODES;
    while (lo < hi) { int mid = (lo + hi) >> 1; if (batch[mid] < t) lo = mid + 1; else hi = mid; }
    gb[t] = lo;
}

__global__ void __launch_bounds__(128) k_pool_part(const unsigned short* __restrict__ Hb,
                                                   const float* __restrict__ scsh,
                                                   const int* __restrict__ gb,
                                                   float* __restrict__ ppart) {
    int g = blockIdx.x, sp = blockIdx.y;
    int c = threadIdx.x;
    float sc = scsh[c], sh = scsh[HDIM + c];
    int s = gb[g], e = gb[g + 1];
    float acc = 0.f;
    for (int i = s + sp; i < e; i += POOL_SPLIT)
        acc += fmaxf(0.f, b2f(Hb[(size_t)i * HDIM + c]) * sc + sh);
    ppart[(g * POOL_SPLIT + sp) * HDIM + c] = acc;
}

__global__ void __launch_bounds__(128) k_pool_final(const int* __restrict__ gb,
                                                    const float* __restrict__ ppart,
                                                    float* __restrict__ pooled) {
    int g = blockIdx.x, c = threadIdx.x;
    float s = 0.f;
    for (int sp = 0; sp < POOL_SPLIT; ++sp) s += ppart[(g * POOL_SPLIT + sp) * HDIM + c];
    int cnt = gb[g + 1] - gb[g]; if (cnt < 1) cnt = 1;
    pooled[g * HDIM + c] = s / (float)cnt;
}

__global__ void __launch_bounds__(128) k_lin(const float* __restrict__ pooled,
                                             const float* __restrict__ W,
                                             const float* __restrict__ bvec,
                                             float* __restrict__ out) {
    __shared__ float p[HDIM];
    int g = blockIdx.x, t = threadIdx.x;
    p[t] = pooled[g * HDIM + t];
    __syncthreads();
    if (t < NCLASS) {
        float acc = bvec[t];
        for (int k = 0; k < HDIM; ++k) acc += p[k] * W[k * NCLASS + t];
        out[g * NCLASS + t] = acc;
    }
}

// ---------------- launch ----------------

extern "C" void kernel_launch(void* const* d_in, const int* in_sizes, int n_in,
                              void* d_out, int out_size, void* d_ws, size_t ws_size,
                              hipStream_t stream) {
    const float* x     = (const float*)d_in[0];
    const int*   eidx  = (const int*)d_in[1];
    const int*   batch = (const int*)d_in[2];
    const float* Wl    = (const float*)d_in[3];
    const float* bl    = (const float*)d_in[4];
    const float* Wr    = (const float*)d_in[5];
    const float* gamma = (const float*)d_in[6];
    const float* beta  = (const float*)d_in[7];
    const float* linW  = (const float*)d_in[8];
    const float* linb  = (const float*)d_in[9];
    float* out = (float*)d_out;

    const int* src = eidx;
    const int* dst = eidx + N_EDGES;

    char* p = (char*)d_ws;
    auto alloc = [&](size_t bytes) { char* r = p; p += (bytes + 255) & ~(size_t)255; return r; };
    unsigned short* Xb   = (unsigned short*)alloc((size_t)N_NODES * HDIM * 2);
    unsigned char*  X8   = (unsigned char*)alloc((size_t)N_NODES * HDIM);
    unsigned short* AGGb = (unsigned short*)alloc((size_t)N_NODES * HDIM * 2);
    unsigned short* HbA  = (unsigned short*)alloc((size_t)N_NODES * HDIM * 2);
    unsigned short* HbB  = (unsigned short*)alloc((size_t)N_NODES * HDIM * 2);
    unsigned short* Wtb  = (unsigned short*)alloc((size_t)NLAYER * 2 * HDIM * HDIM * 2);
    int*   row_off = (int*)alloc((N_NODES + 2) * 4);
    int*   col     = (int*)alloc((size_t)N_EDGES * 4);
    int2v* P       = (int2v*)alloc((size_t)N_EDGES * 8);
    int*   bcnt    = (int*)alloc(NBUCK * 4);
    int*   boff    = (int*)alloc((NBUCK + 1) * 4);
    int*   bcur    = (int*)alloc(NBUCK * 4);
    int*   gb      = (int*)alloc((NGRAPH + 2) * 4);
    float* pstat   = (float*)alloc((size_t)NBLK_G * 256 * 4);
    float* red32   = (float*)alloc(32 * 256 * 4);
    float* scsh    = (float*)alloc(2 * HDIM * 4);
    float* ppart   = (float*)alloc((size_t)NGRAPH * POOL_SPLIT * HDIM * 4);
    float* pooled  = (float*)alloc(NGRAPH * HDIM * 4);

    // ---- CSR build v3 ----
    hipMemsetAsync(bcnt, 0, NBUCK * sizeof(int), stream);
    k_hist<<<KC_BLOCKS, 256, 0, stream>>>(dst, bcnt);
    k_bscan<<<1, 64, 0, stream>>>(bcnt, boff, bcur, row_off);
    k_part<<<KC_BLOCKS, 256, 0, stream>>>(src, dst, bcur, P);
    k_bucket<<<NBUCK, 1024, 0, stream>>>(P, boff, row_off, col);

    // ---- one-time converts ----
    k_cvt_x<<<N_NODES * HDIM / 4 / 256, 256, 0, stream>>>(x, Xb, (unsigned int*)X8);
    k_cvt_w<<<NLAYER * 2 * HDIM * HDIM / 256, 256, 0, stream>>>(Wl, Wr, Wtb);
    k_gbound<<<3, 64, 0, stream>>>(batch, gb);

    // ---- layer 0 ----
    k_agg8<<<N_NODES / 32, 256, 0, stream>>>(X8, row_off, col, AGGb);
    k_gemm_l0<<<NBLK_G, 512, 0, stream>>>(AGGb, Xb, Wtb, bl, HbA, pstat);
    k_red1<<<32, 256, 0, stream>>>(pstat, red32);
    k_stats_final<<<1, 128, 0, stream>>>(red32, gamma, beta, scsh);

    // ---- layers 1..5 ----
    unsigned short* Hcur = HbA;
    for (int l = 1; l < NLAYER; ++l) {
        unsigned short* Hout = (l & 1) ? HbB : HbA;
        k_bnx8<<<N_NODES * HDIM / 8 / 256, 256, 0, stream>>>(Hcur, scsh, (int2v*)X8);
        k_agg8<<<N_NODES / 32, 256, 0, stream>>>(X8, row_off, col, AGGb);
        k_gemm_fuse<<<NBLK_G, 512, 0, stream>>>(
            AGGb, Hcur, scsh, Wtb + (size_t)l * 2 * HDIM * HDIM, bl + (size_t)l * HDIM,
            Hout, pstat);
        k_red1<<<32, 256, 0, stream>>>(pstat, red32);
        k_stats_final<<<1, 128, 0, stream>>>(red32, gamma + (size_t)l * HDIM,
                                             beta + (size_t)l * HDIM, scsh);
        Hcur = Hout;
    }

    // ---- pool + classifier ----
    k_pool_part<<<dim3(NGRAPH, POOL_SPLIT), 128, 0, stream>>>(Hcur, scsh, gb, ppart);
    k_pool_final<<<NGRAPH, 128, 0, stream>>>(gb, ppart, pooled);
    k_lin<<<NGRAPH, 128, 0, stream>>>(pooled, linW, linb, out);
}